// Round 20
// baseline (141.425 us; speedup 1.0000x reference)
//
#include <hip/hip_runtime.h>
#include <hip/hip_fp16.h>

// SoftFreezeAttention on MI355X (gfx950).
// out = softmax_rows(exp(-cdist(X,P)/efft)) @ V  with NO max-subtraction
// (reference underflows to 0; computed honestly).
//
// All-fp8 two-pass pipeline (chunks=1):
//   prep_all: X->X8+x2, P->P8+p2, V->Vt8 (fp8, transposed, n-PERMUTED), invt
//   passA: fp8 GEMM X8.P8^T -> W8 = exp(-dist*invt), N-loop x8, T14
//          epilogue-prefetch, DIRECT permuted fp8 dword nt-stores, rowsum
//          partials via Ws LDS slab.
//   rowsum_k; passB: fp8 GEMM O^T = Vt8 . W8^T (permutation-invariant
//          contraction), transpose + normalize.
//
// History: R11 159.3 -> R14 154.4 -> R17 +launch_bounds(256,2) 154.08 ->
// R18 +T14 guarded 153.9 -> R19 epilogue diet (direct permuted fp8 stores,
// no f16 LDS round-trip, Ws[128][36] rowsum slab): 140.3 (passA 93->79,
// MfmaUtil 35%, VGPR 104). Both GEMMs now at/above the m97-structure
// ceiling (~40%/58% of the 2.19PF fp8 ubench).
// R20 (final trims): (a) passA nrep 4->8, grid 512 = exactly 2 blk/CU in
// one residency round (halves prologues, kills 2nd-round tail); (b) x2
// loads hoisted to 4x float4 per thread (was 16 scalars).

typedef _Float16 f16;
typedef _Float16 f16x8 __attribute__((ext_vector_type(8)));
typedef float f32x4 __attribute__((ext_vector_type(4)));
typedef int i32x4 __attribute__((ext_vector_type(4)));
typedef unsigned char u8;

#define DEV __device__ __forceinline__

DEV void gload16(const void* g, void* l) {
  __builtin_amdgcn_global_load_lds(
      (const __attribute__((address_space(1))) void*)g,
      (__attribute__((address_space(3))) void*)l, 16, 0, 0);
}

// pack 4 f32 -> 4 fp8 e4m3 bytes (OCP), little-endian [a,b,c,d]
DEV int pack4_fp8(float a, float b, float c, float d) {
  int lo = __builtin_amdgcn_cvt_pk_fp8_f32(a, b, 0, false);
  int hi = __builtin_amdgcn_cvt_pk_fp8_f32(c, d, 0, false);
  return (hi << 16) | (lo & 0xffff);
}

// ---------------------------------------------------------------- fused prep

DEV void row_pack(const float* __restrict__ src, u8* __restrict__ dst,
                  float* __restrict__ sq, int blk) {
  int row  = blk * 4 + (threadIdx.x >> 6);
  int lane = threadIdx.x & 63;
  const float* r = src + (size_t)row * 512 + lane * 8;
  float4 a = *(const float4*)r;
  float4 b = *(const float4*)(r + 4);
  int2 pk;
  pk.x = pack4_fp8(a.x, a.y, a.z, a.w);
  pk.y = pack4_fp8(b.x, b.y, b.z, b.w);
  *(int2*)(dst + (size_t)row * 512 + lane * 8) = pk;
  float ss = a.x*a.x + a.y*a.y + a.z*a.z + a.w*a.w
           + b.x*b.x + b.y*b.y + b.z*b.z + b.w*b.w;
  ss += __shfl_xor(ss, 1);  ss += __shfl_xor(ss, 2);  ss += __shfl_xor(ss, 4);
  ss += __shfl_xor(ss, 8);  ss += __shfl_xor(ss, 16); ss += __shfl_xor(ss, 32);
  if (lane == 0) sq[row] = ss;
}

__global__ __launch_bounds__(256) void prep_all(
    const float* __restrict__ x, const float* __restrict__ pos,
    const float* __restrict__ val, const float* __restrict__ T,
    const float* __restrict__ ns,
    u8* __restrict__ X8, u8* __restrict__ P8, u8* __restrict__ Vt8,
    float* __restrict__ x2, float* __restrict__ p2,
    float* __restrict__ invt) {
  __shared__ f16 Tt[64][72];
  int b = blockIdx.x;
  if (b < 4096) {                      // X: 16384 rows
    row_pack(x, X8, x2, b);
  } else if (b < 5120) {               // P: 4096 rows
    row_pack(pos, P8, p2, b - 4096);
  } else if (b < 5632) {               // Vt: 512 64x64 tiles, pi-permuted n:
    // Vt8[d][blk*64 + r*4 + nt] = fp8(V[blk*64 + nt*16 + r][d])
    int id = b - 5120;
    int n0 = (id & 63) * 64, d0 = (id >> 6) * 64;
    int t = threadIdx.x;
#pragma unroll
    for (int rr = 0; rr < 4; ++rr) {
      int r  = (t >> 4) + rr * 16;
      int cq = t & 15;
      float4 v = *(const float4*)(val + (size_t)(n0 + r) * 512 + d0 + cq * 4);
      Tt[cq*4+0][r] = (f16)v.x; Tt[cq*4+1][r] = (f16)v.y;
      Tt[cq*4+2][r] = (f16)v.z; Tt[cq*4+3][r] = (f16)v.w;
    }
    __syncthreads();
    int rd = t >> 2, part = t & 3;   // dest 16B chunk q = part*16 + j
    int p4 = part * 4;
    i32x4 pk;
    // byte j of chunk: src n-local = (j&3)*16 + p4 + (j>>2)
    pk.x = pack4_fp8((float)Tt[rd][p4+0], (float)Tt[rd][16+p4+0],
                     (float)Tt[rd][32+p4+0], (float)Tt[rd][48+p4+0]);
    pk.y = pack4_fp8((float)Tt[rd][p4+1], (float)Tt[rd][16+p4+1],
                     (float)Tt[rd][32+p4+1], (float)Tt[rd][48+p4+1]);
    pk.z = pack4_fp8((float)Tt[rd][p4+2], (float)Tt[rd][16+p4+2],
                     (float)Tt[rd][32+p4+2], (float)Tt[rd][48+p4+2]);
    pk.w = pack4_fp8((float)Tt[rd][p4+3], (float)Tt[rd][16+p4+3],
                     (float)Tt[rd][32+p4+3], (float)Tt[rd][48+p4+3]);
    *(i32x4*)(Vt8 + (size_t)(d0 + rd) * 4096 + n0 + part * 16) = pk;
  } else {                             // invt: 16 blocks x 256
    int i = (b - 5632) * 256 + threadIdx.x;
    invt[i] = 1.0f / ((fabsf(T[i]) + 0.1f) * ns[i]);
  }
}

// ------------------------------------------------- main GEMM (C = A . B^T form)
// All-fp8. 128x128 tile, 4 waves 2x2, 4x4 16x16x32 frags/wave.
// K-tile = 128 B. LDS dbuf [buf0|buf1] = 64KB. Tiles [128 r][128 B];
// 16B-chunk o of row r stored at o^(r&7); global_load_lds pre-swizzled src.
// 2-phase: stage(next) BEFORE compute(cur), one barrier/iter (unroll 2).
// EPI 0: N-loop nrep=8 (grid 512 = exactly 2 blk/CU, one round); T14
//        prefetch of j+1's tile0 into buf0 before j's epilogue; epilogue =
//        direct permuted fp8 stores + Ws[128][36] f32 rowsum slab (buf1).
// __launch_bounds__(256,2): hard 2-blocks/CU floor (VGPR cap 128).
template <int EPI>
__global__ __launch_bounds__(256, 2) void gemm_bt(
    const void* __restrict__ A, const void* __restrict__ B, int Kb, int gx,
    const float* __restrict__ x2, const float* __restrict__ p2,
    const float* __restrict__ invt, u8* __restrict__ Wout,
    float* __restrict__ Wpart,
    const float* __restrict__ rowsum, float* __restrict__ outp) {
  __shared__ __align__(16) char smem[65536];
  char* As = smem;            // +cur: 0 or 32768
  char* Bs = smem + 16384;

  const int nwg = gridDim.x;
  const int sid = (blockIdx.x & 7) * (nwg >> 3) + (blockIdx.x >> 3);
  const int bx = sid % gx, by = sid / gx;

  const int tid = threadIdx.x, lane = tid & 63, w = tid >> 6;
  const int wrow = (w >> 1) * 64, wcol = (w & 1) * 64;
  const int g = lane >> 4, r15 = lane & 15;
  const int m0 = by * 128;

  const char* Ablk = (const char*)A + (size_t)m0 * Kb;

  const int lr = lane >> 3;
  const int lo = (lane & 7) ^ lr;
  const char* aSrc[4]; char* aDst[4]; char* bDst[4];
  int srow[4];
#pragma unroll
  for (int i = 0; i < 4; ++i) {
    int cb  = w * 4 + i;
    srow[i] = cb * 8 + lr;
    aSrc[i] = Ablk + (size_t)srow[i] * Kb + 16 * lo;
    aDst[i] = As + cb * 1024;
    bDst[i] = Bs + cb * 1024;
  }

  int abase[4], asw[4], bbase[4], bsw[4];
#pragma unroll
  for (int mt = 0; mt < 4; ++mt) {
    int r = wrow + mt * 16 + r15;
    abase[mt] = r * 128; asw[mt] = (r & 7) << 4;
    int rb = wcol + mt * 16 + r15;
    bbase[mt] = rb * 128; bsw[mt] = (rb & 7) << 4;
  }

  const int NIT = Kb >> 7;
  constexpr int nrep = (EPI == 0) ? 8 : 1;

  // prologue: stage tile0 of j=0 into buf0
  {
    const char* Bblk0 = (const char*)B + (size_t)(bx * nrep * 128) * Kb;
#pragma unroll
    for (int i = 0; i < 4; ++i) gload16(aSrc[i], aDst[i]);
#pragma unroll
    for (int i = 0; i < 4; ++i)
      gload16(Bblk0 + (size_t)srow[i] * Kb + 16 * lo, bDst[i]);
  }

  for (int j = 0; j < nrep; ++j) {
    const int bxj = bx * nrep + j;
    const int n0 = bxj * 128;
    const char* Bblk = (const char*)B + (size_t)n0 * Kb;
    const char* bSrc[4];
#pragma unroll
    for (int i = 0; i < 4; ++i)
      bSrc[i] = Bblk + (size_t)srow[i] * Kb + 16 * lo;

    // drains tile0 gloads (prologue or T14 prefetch); retires previous
    // epilogue's Ws(buf1) reads before it=0 stages buf1.
    __syncthreads();
    f32x4 acc[4][4] = {};

#pragma unroll 2
    for (int it = 0; it < NIT; ++it) {
      const int cur = (it & 1) << 15;
      const int nxt = cur ^ 32768;
      if (it + 1 < NIT) {                  // issue next-tile loads FIRST
        const int kb1 = (it + 1) << 7;
#pragma unroll
        for (int i = 0; i < 4; ++i) gload16(aSrc[i] + kb1, aDst[i] + nxt);
#pragma unroll
        for (int i = 0; i < 4; ++i) gload16(bSrc[i] + kb1, bDst[i] + nxt);
      }
      const char* As_ = As + cur;
      const char* Bs_ = Bs + cur;
#pragma unroll
      for (int ks = 0; ks < 4; ++ks) {     // 4 k-slices of K=32 fp8
        long aL[4], bL[4];
#pragma unroll
        for (int mt = 0; mt < 4; ++mt)
          aL[mt] = *(const long*)(As_ + (abase[mt] + ((32 * ks + 8 * g) ^ asw[mt])));
#pragma unroll
        for (int nt = 0; nt < 4; ++nt)
          bL[nt] = *(const long*)(Bs_ + (bbase[nt] + ((32 * ks + 8 * g) ^ bsw[nt])));
#pragma unroll
        for (int mt = 0; mt < 4; ++mt)
#pragma unroll
          for (int nt = 0; nt < 4; ++nt)
            acc[mt][nt] = __builtin_amdgcn_mfma_f32_16x16x32_fp8_fp8(aL[mt], bL[nt],
                                                                     acc[mt][nt], 0, 0, 0);
      }
      __syncthreads();
    }
    // after the final barrier all buffer reads are retired.

    if constexpr (EPI == 0) {
      // T14 prefetch: j+1's tile0 into buf0 NOW; epilogue covers latency.
      if (j + 1 < nrep) {
        const char* Bn = (const char*)B + (size_t)((bxj + 1) * 128) * Kb;
#pragma unroll
        for (int i = 0; i < 4; ++i) gload16(aSrc[i], aDst[i]);
#pragma unroll
        for (int i = 0; i < 4; ++i)
          gload16(Bn + (size_t)srow[i] * Kb + 16 * lo, bDst[i]);
      }
      // ---- epilogue (no f16 round-trip): per (mt,reg): 4x exp -> pack4
      // straight to fp8 -> ONE permuted nt dword store
      // (W col' = wcol + 4*r15 + nt  <->  orig col wcol + nt*16 + r15,
      // matching prep_vt's pi so pass B's contraction is invariant).
      // Row-partials to Ws[128][36] f32 in buf1 (16B-aligned rows).
      float* Ws = (float*)(smem + 32768);
      float p2v[4], itv[4];
#pragma unroll
      for (int nt = 0; nt < 4; ++nt) {
        int n = n0 + wcol + nt * 16 + r15;
        p2v[nt] = p2[n]; itv[nt] = invt[n];
      }
      u8* wbase = Wout + n0 + wcol + 4 * r15;
#pragma unroll
      for (int mt = 0; mt < 4; ++mt) {
        float4 xx4 = *(const float4*)&x2[m0 + wrow + mt * 16 + g * 4];
#pragma unroll
        for (int reg = 0; reg < 4; ++reg) {
          int ml = wrow + mt * 16 + g * 4 + reg;
          float xx = reg == 0 ? xx4.x : reg == 1 ? xx4.y : reg == 2 ? xx4.z
                                                                    : xx4.w;
          float wv0, wv1, wv2, wv3;
          {
            float d2 = xx + p2v[0] - 2.0f * acc[mt][0][reg];
            wv0 = __expf(-__builtin_amdgcn_sqrtf(fmaxf(d2, 0.0f)) * itv[0]);
            d2 = xx + p2v[1] - 2.0f * acc[mt][1][reg];
            wv1 = __expf(-__builtin_amdgcn_sqrtf(fmaxf(d2, 0.0f)) * itv[1]);
            d2 = xx + p2v[2] - 2.0f * acc[mt][2][reg];
            wv2 = __expf(-__builtin_amdgcn_sqrtf(fmaxf(d2, 0.0f)) * itv[2]);
            d2 = xx + p2v[3] - 2.0f * acc[mt][3][reg];
            wv3 = __expf(-__builtin_amdgcn_sqrtf(fmaxf(d2, 0.0f)) * itv[3]);
          }
          int dw = pack4_fp8(wv0, wv1, wv2, wv3);
          __builtin_nontemporal_store(dw, (int*)(wbase + (size_t)(m0 + ml) * 4096));
          Ws[ml * 36 + (w & 1) * 16 + r15] = wv0 + wv1 + wv2 + wv3;
        }
      }
      __syncthreads();
      {
        int r = tid >> 1, half = tid & 1;
        const float* sp = Ws + r * 36 + half * 16;
        float4 a0 = *(const float4*)(sp);
        float4 a1 = *(const float4*)(sp + 4);
        float4 a2 = *(const float4*)(sp + 8);
        float4 a3 = *(const float4*)(sp + 12);
        float s = a0.x+a0.y+a0.z+a0.w + a1.x+a1.y+a1.z+a1.w
                + a2.x+a2.y+a2.z+a2.w + a3.x+a3.y+a3.z+a3.w;
        Wpart[(size_t)(m0 + r) * 64 + bxj * 2 + half] = s;
      }
    } else {
      // ---- pass B epilogue: O^T transpose via per-wave LDS + normalize
      float* Tb = (float*)(smem) + w * (32 * 66);
      const int dl = lane & 31, half = lane >> 5;
#pragma unroll
      for (int h = 0; h < 2; ++h) {
#pragma unroll
        for (int mh = 0; mh < 2; ++mh) {
          int mt = h * 2 + mh;
#pragma unroll
          for (int nt = 0; nt < 4; ++nt)
#pragma unroll
            for (int reg = 0; reg < 4; ++reg)
              Tb[(mh * 16 + g * 4 + reg) * 66 + nt * 16 + r15] = acc[mt][nt][reg];
        }
#pragma unroll
        for (int rr = 0; rr < 32; ++rr) {
          int mloc = rr * 2 + half;
          float v = Tb[dl * 66 + mloc];
          int mg = n0 + wcol + mloc;
          int dg = m0 + wrow + h * 32 + dl;
          float nrm = 1.0f / (rowsum[mg] + 1e-8f);
          __builtin_nontemporal_store(v * nrm, &outp[(size_t)mg * 512 + dg]);
        }
        __syncthreads();  // Tb reused next h
      }
    }
  }
}

// rowsum[m] = sum of 64 partials
__global__ __launch_bounds__(256) void rowsum_k(const float* __restrict__ Wpart,
                                                float* __restrict__ rowsum) {
  int row  = blockIdx.x * 4 + (threadIdx.x >> 6);
  int lane = threadIdx.x & 63;
  float v = Wpart[(size_t)row * 64 + lane];
  v += __shfl_xor(v, 1);  v += __shfl_xor(v, 2);  v += __shfl_xor(v, 4);
  v += __shfl_xor(v, 8);  v += __shfl_xor(v, 16); v += __shfl_xor(v, 32);
  if (lane == 0) rowsum[row] = v;
}

// ---------------------------------------------------------------------- launch

extern "C" void kernel_launch(void* const* d_in, const int* in_sizes, int n_in,
                              void* d_out, int out_size, void* d_ws, size_t ws_size,
                              hipStream_t stream) {
  const float* x   = (const float*)d_in[0];
  const float* pos = (const float*)d_in[1];
  const float* val = (const float*)d_in[2];
  const float* tmp = (const float*)d_in[3];
  const float* nsc = (const float*)d_in[4];
  float* out = (float*)d_out;

  char* p = (char*)d_ws;
  u8*    X8     = (u8*)p;    p += (size_t)16384 * 512;
  u8*    P8     = (u8*)p;    p += (size_t)4096 * 512;
  u8*    Vt8    = (u8*)p;    p += (size_t)512 * 4096;
  float* x2     = (float*)p; p += (size_t)16384 * 4;
  float* p2     = (float*)p; p += (size_t)4096 * 4;
  float* invt   = (float*)p; p += (size_t)4096 * 4;
  float* rowsum = (float*)p; p += (size_t)16384 * 4;
  float* Wpart  = (float*)p; p += (size_t)16384 * 64 * 4;
  u8*    W8     = (u8*)p;
  size_t fixed  = (size_t)(p - (char*)d_ws);
  size_t wfull  = (size_t)16384 * 4096;   // fp8 W

  if (fixed + wfull > ws_size) return;

  prep_all<<<5648, 256, 0, stream>>>(x, pos, val, tmp, nsc,
                                     X8, P8, Vt8, x2, p2, invt);

  // pass A: Kb = 512 fp8 bytes/row, NIT = 4, N-loop x8 -> grid 4 * 128 = 512
  gemm_bt<0><<<4 * 128, 256, 0, stream>>>(
      X8, P8, 512, 4, x2, p2, invt, W8, Wpart, nullptr, nullptr);
  rowsum_k<<<4096, 256, 0, stream>>>(Wpart, rowsum);
  // pass B: Kb = 4096 fp8 bytes/row, NIT = 32
  gemm_bt<1><<<128 * 4, 256, 0, stream>>>(
      Vt8, W8, 4096, 128, nullptr, nullptr, nullptr, nullptr, nullptr,
      rowsum, out);
}

// Round 21
// 140.329 us; speedup vs baseline: 1.0078x; 1.0078x over previous
//
#include <hip/hip_runtime.h>
#include <hip/hip_fp16.h>

// SoftFreezeAttention on MI355X (gfx950).
// out = softmax_rows(exp(-cdist(X,P)/efft)) @ V  with NO max-subtraction
// (reference underflows to 0; computed honestly).
//
// All-fp8 two-pass pipeline (chunks=1):
//   prep_all: X->X8+x2, P->P8+p2, V->Vt8 (fp8, transposed, n-PERMUTED), invt
//   passA: fp8 GEMM X8.P8^T -> W8 = exp(-dist*invt), N-loop x4, T14
//          epilogue-prefetch, DIRECT permuted fp8 dword nt-stores (no f16
//          LDS round-trip), rowsum partials via small Ws LDS slab.
//   rowsum_k; passB: fp8 GEMM O^T = Vt8 . W8^T (contraction over permuted n
//          invariant: both operands share the permutation), transpose+norm.
//
// FINAL (R21 = R19 verbatim, session best 140.3us):
// R11 159.3 -> R14 154.4 -> R17 +launch_bounds(256,2) 154.08 -> R18 +T14
// guarded 153.9 -> R19 epilogue diet 140.3 -> R20 nrep=8 NEUTRAL (141.4,
// reverted). Plateau: passA 79us = 40% fp8 ubench (2-barrier-structure
// band; floor = 31us MFMA + ~25us irreducible exp-epilogue VALU), passB
// 54us = 58%, preps ~6us HBM-bound. Further gains need the 256^2 8-phase
// schedule rebuilt under a <=128-VGPR budget (graft paths measured
// exhausted: R12/R13/R15/R16/R20).

typedef _Float16 f16;
typedef _Float16 f16x8 __attribute__((ext_vector_type(8)));
typedef float f32x4 __attribute__((ext_vector_type(4)));
typedef int i32x4 __attribute__((ext_vector_type(4)));
typedef unsigned char u8;

#define DEV __device__ __forceinline__

DEV void gload16(const void* g, void* l) {
  __builtin_amdgcn_global_load_lds(
      (const __attribute__((address_space(1))) void*)g,
      (__attribute__((address_space(3))) void*)l, 16, 0, 0);
}

// pack 4 f32 -> 4 fp8 e4m3 bytes (OCP), little-endian [a,b,c,d]
DEV int pack4_fp8(float a, float b, float c, float d) {
  int lo = __builtin_amdgcn_cvt_pk_fp8_f32(a, b, 0, false);
  int hi = __builtin_amdgcn_cvt_pk_fp8_f32(c, d, 0, false);
  return (hi << 16) | (lo & 0xffff);
}

// ---------------------------------------------------------------- fused prep

DEV void row_pack(const float* __restrict__ src, u8* __restrict__ dst,
                  float* __restrict__ sq, int blk) {
  int row  = blk * 4 + (threadIdx.x >> 6);
  int lane = threadIdx.x & 63;
  const float* r = src + (size_t)row * 512 + lane * 8;
  float4 a = *(const float4*)r;
  float4 b = *(const float4*)(r + 4);
  int2 pk;
  pk.x = pack4_fp8(a.x, a.y, a.z, a.w);
  pk.y = pack4_fp8(b.x, b.y, b.z, b.w);
  *(int2*)(dst + (size_t)row * 512 + lane * 8) = pk;
  float ss = a.x*a.x + a.y*a.y + a.z*a.z + a.w*a.w
           + b.x*b.x + b.y*b.y + b.z*b.z + b.w*b.w;
  ss += __shfl_xor(ss, 1);  ss += __shfl_xor(ss, 2);  ss += __shfl_xor(ss, 4);
  ss += __shfl_xor(ss, 8);  ss += __shfl_xor(ss, 16); ss += __shfl_xor(ss, 32);
  if (lane == 0) sq[row] = ss;
}

__global__ __launch_bounds__(256) void prep_all(
    const float* __restrict__ x, const float* __restrict__ pos,
    const float* __restrict__ val, const float* __restrict__ T,
    const float* __restrict__ ns,
    u8* __restrict__ X8, u8* __restrict__ P8, u8* __restrict__ Vt8,
    float* __restrict__ x2, float* __restrict__ p2,
    float* __restrict__ invt) {
  __shared__ f16 Tt[64][72];
  int b = blockIdx.x;
  if (b < 4096) {                      // X: 16384 rows
    row_pack(x, X8, x2, b);
  } else if (b < 5120) {               // P: 4096 rows
    row_pack(pos, P8, p2, b - 4096);
  } else if (b < 5632) {               // Vt: 512 64x64 tiles, pi-permuted n:
    // Vt8[d][blk*64 + r*4 + nt] = fp8(V[blk*64 + nt*16 + r][d])
    int id = b - 5120;
    int n0 = (id & 63) * 64, d0 = (id >> 6) * 64;
    int t = threadIdx.x;
#pragma unroll
    for (int rr = 0; rr < 4; ++rr) {
      int r  = (t >> 4) + rr * 16;
      int cq = t & 15;
      float4 v = *(const float4*)(val + (size_t)(n0 + r) * 512 + d0 + cq * 4);
      Tt[cq*4+0][r] = (f16)v.x; Tt[cq*4+1][r] = (f16)v.y;
      Tt[cq*4+2][r] = (f16)v.z; Tt[cq*4+3][r] = (f16)v.w;
    }
    __syncthreads();
    int rd = t >> 2, part = t & 3;   // dest 16B chunk q = part*16 + j
    int p4 = part * 4;
    i32x4 pk;
    // byte j of chunk: src n-local = (j&3)*16 + p4 + (j>>2)
    pk.x = pack4_fp8((float)Tt[rd][p4+0], (float)Tt[rd][16+p4+0],
                     (float)Tt[rd][32+p4+0], (float)Tt[rd][48+p4+0]);
    pk.y = pack4_fp8((float)Tt[rd][p4+1], (float)Tt[rd][16+p4+1],
                     (float)Tt[rd][32+p4+1], (float)Tt[rd][48+p4+1]);
    pk.z = pack4_fp8((float)Tt[rd][p4+2], (float)Tt[rd][16+p4+2],
                     (float)Tt[rd][32+p4+2], (float)Tt[rd][48+p4+2]);
    pk.w = pack4_fp8((float)Tt[rd][p4+3], (float)Tt[rd][16+p4+3],
                     (float)Tt[rd][32+p4+3], (float)Tt[rd][48+p4+3]);
    *(i32x4*)(Vt8 + (size_t)(d0 + rd) * 4096 + n0 + part * 16) = pk;
  } else {                             // invt: 16 blocks x 256
    int i = (b - 5632) * 256 + threadIdx.x;
    invt[i] = 1.0f / ((fabsf(T[i]) + 0.1f) * ns[i]);
  }
}

// ------------------------------------------------- main GEMM (C = A . B^T form)
// All-fp8. 128x128 tile, 4 waves 2x2, 4x4 16x16x32 frags/wave.
// K-tile = 128 B. LDS dbuf [buf0|buf1] = 64KB. Tiles [128 r][128 B];
// 16B-chunk o of row r stored at o^(r&7); global_load_lds pre-swizzled src.
// 2-phase: stage(next) BEFORE compute(cur), one barrier/iter (unroll 2).
// EPI 0: N-loop nrep=4; T14 prefetch of j+1's tile0 into buf0 before j's
//        epilogue; epilogue = direct permuted fp8 stores + Ws rowsum slab
//        (buf1, [128][36] f32: pad 36 keeps 16B-aligned rows, 2-way banks).
// __launch_bounds__(256,2): hard 2-blocks/CU floor (VGPR cap 128).
template <int EPI>
__global__ __launch_bounds__(256, 2) void gemm_bt(
    const void* __restrict__ A, const void* __restrict__ B, int Kb, int gx,
    const float* __restrict__ x2, const float* __restrict__ p2,
    const float* __restrict__ invt, u8* __restrict__ Wout,
    float* __restrict__ Wpart,
    const float* __restrict__ rowsum, float* __restrict__ outp) {
  __shared__ __align__(16) char smem[65536];
  char* As = smem;            // +cur: 0 or 32768
  char* Bs = smem + 16384;

  const int nwg = gridDim.x;
  const int sid = (blockIdx.x & 7) * (nwg >> 3) + (blockIdx.x >> 3);
  const int bx = sid % gx, by = sid / gx;

  const int tid = threadIdx.x, lane = tid & 63, w = tid >> 6;
  const int wrow = (w >> 1) * 64, wcol = (w & 1) * 64;
  const int g = lane >> 4, r15 = lane & 15;
  const int m0 = by * 128;

  const char* Ablk = (const char*)A + (size_t)m0 * Kb;

  const int lr = lane >> 3;
  const int lo = (lane & 7) ^ lr;
  const char* aSrc[4]; char* aDst[4]; char* bDst[4];
  int srow[4];
#pragma unroll
  for (int i = 0; i < 4; ++i) {
    int cb  = w * 4 + i;
    srow[i] = cb * 8 + lr;
    aSrc[i] = Ablk + (size_t)srow[i] * Kb + 16 * lo;
    aDst[i] = As + cb * 1024;
    bDst[i] = Bs + cb * 1024;
  }

  int abase[4], asw[4], bbase[4], bsw[4];
#pragma unroll
  for (int mt = 0; mt < 4; ++mt) {
    int r = wrow + mt * 16 + r15;
    abase[mt] = r * 128; asw[mt] = (r & 7) << 4;
    int rb = wcol + mt * 16 + r15;
    bbase[mt] = rb * 128; bsw[mt] = (rb & 7) << 4;
  }

  const int NIT = Kb >> 7;
  constexpr int nrep = (EPI == 0) ? 4 : 1;

  // prologue: stage tile0 of j=0 into buf0
  {
    const char* Bblk0 = (const char*)B + (size_t)(bx * nrep * 128) * Kb;
#pragma unroll
    for (int i = 0; i < 4; ++i) gload16(aSrc[i], aDst[i]);
#pragma unroll
    for (int i = 0; i < 4; ++i)
      gload16(Bblk0 + (size_t)srow[i] * Kb + 16 * lo, bDst[i]);
  }

  for (int j = 0; j < nrep; ++j) {
    const int bxj = bx * nrep + j;
    const int n0 = bxj * 128;
    const char* Bblk = (const char*)B + (size_t)n0 * Kb;
    const char* bSrc[4];
#pragma unroll
    for (int i = 0; i < 4; ++i)
      bSrc[i] = Bblk + (size_t)srow[i] * Kb + 16 * lo;

    // drains tile0 gloads (prologue or T14 prefetch); retires previous
    // epilogue's Ws(buf1) reads before it=0 stages buf1.
    __syncthreads();
    f32x4 acc[4][4] = {};

#pragma unroll 2
    for (int it = 0; it < NIT; ++it) {
      const int cur = (it & 1) << 15;
      const int nxt = cur ^ 32768;
      if (it + 1 < NIT) {                  // issue next-tile loads FIRST
        const int kb1 = (it + 1) << 7;
#pragma unroll
        for (int i = 0; i < 4; ++i) gload16(aSrc[i] + kb1, aDst[i] + nxt);
#pragma unroll
        for (int i = 0; i < 4; ++i) gload16(bSrc[i] + kb1, bDst[i] + nxt);
      }
      const char* As_ = As + cur;
      const char* Bs_ = Bs + cur;
#pragma unroll
      for (int ks = 0; ks < 4; ++ks) {     // 4 k-slices of K=32 fp8
        long aL[4], bL[4];
#pragma unroll
        for (int mt = 0; mt < 4; ++mt)
          aL[mt] = *(const long*)(As_ + (abase[mt] + ((32 * ks + 8 * g) ^ asw[mt])));
#pragma unroll
        for (int nt = 0; nt < 4; ++nt)
          bL[nt] = *(const long*)(Bs_ + (bbase[nt] + ((32 * ks + 8 * g) ^ bsw[nt])));
#pragma unroll
        for (int mt = 0; mt < 4; ++mt)
#pragma unroll
          for (int nt = 0; nt < 4; ++nt)
            acc[mt][nt] = __builtin_amdgcn_mfma_f32_16x16x32_fp8_fp8(aL[mt], bL[nt],
                                                                     acc[mt][nt], 0, 0, 0);
      }
      __syncthreads();
    }
    // after the final barrier all buffer reads are retired.

    if constexpr (EPI == 0) {
      // T14 prefetch: j+1's tile0 into buf0 NOW; epilogue covers latency.
      if (j + 1 < nrep) {
        const char* Bn = (const char*)B + (size_t)((bxj + 1) * 128) * Kb;
#pragma unroll
        for (int i = 0; i < 4; ++i) gload16(aSrc[i], aDst[i]);
#pragma unroll
        for (int i = 0; i < 4; ++i)
          gload16(Bn + (size_t)srow[i] * Kb + 16 * lo, bDst[i]);
      }
      // ---- epilogue (no f16 round-trip): per (mt,reg): 4x exp -> pack4
      // straight to fp8 -> ONE permuted nt dword store
      // (W col' = wcol + 4*r15 + nt  <->  orig col wcol + nt*16 + r15,
      // matching prep_vt's pi so pass B's contraction is invariant).
      // Row-partials to Ws[128][36] f32 in buf1 (16B-aligned rows).
      float* Ws = (float*)(smem + 32768);
      float p2v[4], itv[4];
#pragma unroll
      for (int nt = 0; nt < 4; ++nt) {
        int n = n0 + wcol + nt * 16 + r15;
        p2v[nt] = p2[n]; itv[nt] = invt[n];
      }
      u8* wbase = Wout + n0 + wcol + 4 * r15;
#pragma unroll
      for (int mt = 0; mt < 4; ++mt) {
#pragma unroll
        for (int reg = 0; reg < 4; ++reg) {
          int ml = wrow + mt * 16 + g * 4 + reg;
          float xx = x2[m0 + ml];
          float wv0, wv1, wv2, wv3;
          {
            float d2 = xx + p2v[0] - 2.0f * acc[mt][0][reg];
            wv0 = __expf(-__builtin_amdgcn_sqrtf(fmaxf(d2, 0.0f)) * itv[0]);
            d2 = xx + p2v[1] - 2.0f * acc[mt][1][reg];
            wv1 = __expf(-__builtin_amdgcn_sqrtf(fmaxf(d2, 0.0f)) * itv[1]);
            d2 = xx + p2v[2] - 2.0f * acc[mt][2][reg];
            wv2 = __expf(-__builtin_amdgcn_sqrtf(fmaxf(d2, 0.0f)) * itv[2]);
            d2 = xx + p2v[3] - 2.0f * acc[mt][3][reg];
            wv3 = __expf(-__builtin_amdgcn_sqrtf(fmaxf(d2, 0.0f)) * itv[3]);
          }
          int dw = pack4_fp8(wv0, wv1, wv2, wv3);
          __builtin_nontemporal_store(dw, (int*)(wbase + (size_t)(m0 + ml) * 4096));
          Ws[ml * 36 + (w & 1) * 16 + r15] = wv0 + wv1 + wv2 + wv3;
        }
      }
      __syncthreads();
      {
        int r = tid >> 1, half = tid & 1;
        const float* sp = Ws + r * 36 + half * 16;
        float4 a0 = *(const float4*)(sp);
        float4 a1 = *(const float4*)(sp + 4);
        float4 a2 = *(const float4*)(sp + 8);
        float4 a3 = *(const float4*)(sp + 12);
        float s = a0.x+a0.y+a0.z+a0.w + a1.x+a1.y+a1.z+a1.w
                + a2.x+a2.y+a2.z+a2.w + a3.x+a3.y+a3.z+a3.w;
        Wpart[(size_t)(m0 + r) * 64 + bxj * 2 + half] = s;
      }
    } else {
      // ---- pass B epilogue: O^T transpose via per-wave LDS + normalize
      float* Tb = (float*)(smem) + w * (32 * 66);
      const int dl = lane & 31, half = lane >> 5;
#pragma unroll
      for (int h = 0; h < 2; ++h) {
#pragma unroll
        for (int mh = 0; mh < 2; ++mh) {
          int mt = h * 2 + mh;
#pragma unroll
          for (int nt = 0; nt < 4; ++nt)
#pragma unroll
            for (int reg = 0; reg < 4; ++reg)
              Tb[(mh * 16 + g * 4 + reg) * 66 + nt * 16 + r15] = acc[mt][nt][reg];
        }
#pragma unroll
        for (int rr = 0; rr < 32; ++rr) {
          int mloc = rr * 2 + half;
          float v = Tb[dl * 66 + mloc];
          int mg = n0 + wcol + mloc;
          int dg = m0 + wrow + h * 32 + dl;
          float nrm = 1.0f / (rowsum[mg] + 1e-8f);
          __builtin_nontemporal_store(v * nrm, &outp[(size_t)mg * 512 + dg]);
        }
        __syncthreads();  // Tb reused next h
      }
    }
  }
}

// rowsum[m] = sum of 64 partials
__global__ __launch_bounds__(256) void rowsum_k(const float* __restrict__ Wpart,
                                                float* __restrict__ rowsum) {
  int row  = blockIdx.x * 4 + (threadIdx.x >> 6);
  int lane = threadIdx.x & 63;
  float v = Wpart[(size_t)row * 64 + lane];
  v += __shfl_xor(v, 1);  v += __shfl_xor(v, 2);  v += __shfl_xor(v, 4);
  v += __shfl_xor(v, 8);  v += __shfl_xor(v, 16); v += __shfl_xor(v, 32);
  if (lane == 0) rowsum[row] = v;
}

// ---------------------------------------------------------------------- launch

extern "C" void kernel_launch(void* const* d_in, const int* in_sizes, int n_in,
                              void* d_out, int out_size, void* d_ws, size_t ws_size,
                              hipStream_t stream) {
  const float* x   = (const float*)d_in[0];
  const float* pos = (const float*)d_in[1];
  const float* val = (const float*)d_in[2];
  const float* tmp = (const float*)d_in[3];
  const float* nsc = (const float*)d_in[4];
  float* out = (float*)d_out;

  char* p = (char*)d_ws;
  u8*    X8     = (u8*)p;    p += (size_t)16384 * 512;
  u8*    P8     = (u8*)p;    p += (size_t)4096 * 512;
  u8*    Vt8    = (u8*)p;    p += (size_t)512 * 4096;
  float* x2     = (float*)p; p += (size_t)16384 * 4;
  float* p2     = (float*)p; p += (size_t)4096 * 4;
  float* invt   = (float*)p; p += (size_t)4096 * 4;
  float* rowsum = (float*)p; p += (size_t)16384 * 4;
  float* Wpart  = (float*)p; p += (size_t)16384 * 64 * 4;
  u8*    W8     = (u8*)p;
  size_t fixed  = (size_t)(p - (char*)d_ws);
  size_t wfull  = (size_t)16384 * 4096;   // fp8 W

  if (fixed + wfull > ws_size) return;

  prep_all<<<5648, 256, 0, stream>>>(x, pos, val, tmp, nsc,
                                     X8, P8, Vt8, x2, p2, invt);

  // pass A: Kb = 512 fp8 bytes/row, NIT = 4, N-loop x4 -> grid 8 * 128
  gemm_bt<0><<<8 * 128, 256, 0, stream>>>(
      X8, P8, 512, 8, x2, p2, invt, W8, Wpart, nullptr, nullptr);
  rowsum_k<<<4096, 256, 0, stream>>>(Wpart, rowsum);
  // pass B: Kb = 4096 fp8 bytes/row, NIT = 32
  gemm_bt<1><<<128 * 4, 256, 0, stream>>>(
      Vt8, W8, 4096, 128, nullptr, nullptr, nullptr, nullptr, nullptr,
      rowsum, out);
}

// Round 22
// 136.725 us; speedup vs baseline: 1.0344x; 1.0264x over previous
//
#include <hip/hip_runtime.h>
#include <hip/hip_fp16.h>

// SoftFreezeAttention on MI355X (gfx950).
// out = softmax_rows(exp(-cdist(X,P)/efft)) @ V  with NO max-subtraction
// (reference underflows to 0; computed honestly).
//
// All-fp8 two-pass pipeline (chunks=1):
//   prep_all: X->X8+x2, P->P8+p2, V->Vt8 (fp8, transposed, n-PERMUTED), invt
//   passA: fp8 GEMM X8.P8^T -> W8 = exp(-dist*invt), N-loop x4, T14
//          epilogue-prefetch, DIRECT permuted fp8 dword nt-stores, rowsum
//          partials via Ws LDS slab. R22: EXACT early-exit — expf(-t)==0.0f
//          for t>=104 (6.9e-46 < min denormal 1.4e-45), so d2>=(104/invt)^2
//          => wv bit-exactly 0; wave-uniform __any() skips sqrt/exp (70% of
//          epilogue cycle cost; full path kept for adversarial data).
//   rowsum_k; passB: fp8 GEMM O^T = Vt8 . W8^T (permutation-invariant),
//          transpose + normalize.
//
// History: R11 159.3 -> R14 154.4 -> R17 +launch_bounds(256,2) 154.08 ->
// R18 +T14 153.9 -> R19 epilogue diet 140.3 (BEST, reproduced R21) ->
// R20 nrep8 neutral (reverted). passA 79us: MFMA 31us + epilogue VALU
// ~25us co-dominant -> R22 targets the transcendental chains exactly.

typedef _Float16 f16;
typedef _Float16 f16x8 __attribute__((ext_vector_type(8)));
typedef float f32x4 __attribute__((ext_vector_type(4)));
typedef int i32x4 __attribute__((ext_vector_type(4)));
typedef unsigned char u8;

#define DEV __device__ __forceinline__

DEV void gload16(const void* g, void* l) {
  __builtin_amdgcn_global_load_lds(
      (const __attribute__((address_space(1))) void*)g,
      (__attribute__((address_space(3))) void*)l, 16, 0, 0);
}

// pack 4 f32 -> 4 fp8 e4m3 bytes (OCP), little-endian [a,b,c,d]
DEV int pack4_fp8(float a, float b, float c, float d) {
  int lo = __builtin_amdgcn_cvt_pk_fp8_f32(a, b, 0, false);
  int hi = __builtin_amdgcn_cvt_pk_fp8_f32(c, d, 0, false);
  return (hi << 16) | (lo & 0xffff);
}

// ---------------------------------------------------------------- fused prep

DEV void row_pack(const float* __restrict__ src, u8* __restrict__ dst,
                  float* __restrict__ sq, int blk) {
  int row  = blk * 4 + (threadIdx.x >> 6);
  int lane = threadIdx.x & 63;
  const float* r = src + (size_t)row * 512 + lane * 8;
  float4 a = *(const float4*)r;
  float4 b = *(const float4*)(r + 4);
  int2 pk;
  pk.x = pack4_fp8(a.x, a.y, a.z, a.w);
  pk.y = pack4_fp8(b.x, b.y, b.z, b.w);
  *(int2*)(dst + (size_t)row * 512 + lane * 8) = pk;
  float ss = a.x*a.x + a.y*a.y + a.z*a.z + a.w*a.w
           + b.x*b.x + b.y*b.y + b.z*b.z + b.w*b.w;
  ss += __shfl_xor(ss, 1);  ss += __shfl_xor(ss, 2);  ss += __shfl_xor(ss, 4);
  ss += __shfl_xor(ss, 8);  ss += __shfl_xor(ss, 16); ss += __shfl_xor(ss, 32);
  if (lane == 0) sq[row] = ss;
}

__global__ __launch_bounds__(256) void prep_all(
    const float* __restrict__ x, const float* __restrict__ pos,
    const float* __restrict__ val, const float* __restrict__ T,
    const float* __restrict__ ns,
    u8* __restrict__ X8, u8* __restrict__ P8, u8* __restrict__ Vt8,
    float* __restrict__ x2, float* __restrict__ p2,
    float* __restrict__ invt) {
  __shared__ f16 Tt[64][72];
  int b = blockIdx.x;
  if (b < 4096) {                      // X: 16384 rows
    row_pack(x, X8, x2, b);
  } else if (b < 5120) {               // P: 4096 rows
    row_pack(pos, P8, p2, b - 4096);
  } else if (b < 5632) {               // Vt: 512 64x64 tiles, pi-permuted n:
    // Vt8[d][blk*64 + r*4 + nt] = fp8(V[blk*64 + nt*16 + r][d])
    int id = b - 5120;
    int n0 = (id & 63) * 64, d0 = (id >> 6) * 64;
    int t = threadIdx.x;
#pragma unroll
    for (int rr = 0; rr < 4; ++rr) {
      int r  = (t >> 4) + rr * 16;
      int cq = t & 15;
      float4 v = *(const float4*)(val + (size_t)(n0 + r) * 512 + d0 + cq * 4);
      Tt[cq*4+0][r] = (f16)v.x; Tt[cq*4+1][r] = (f16)v.y;
      Tt[cq*4+2][r] = (f16)v.z; Tt[cq*4+3][r] = (f16)v.w;
    }
    __syncthreads();
    int rd = t >> 2, part = t & 3;   // dest 16B chunk q = part*16 + j
    int p4 = part * 4;
    i32x4 pk;
    // byte j of chunk: src n-local = (j&3)*16 + p4 + (j>>2)
    pk.x = pack4_fp8((float)Tt[rd][p4+0], (float)Tt[rd][16+p4+0],
                     (float)Tt[rd][32+p4+0], (float)Tt[rd][48+p4+0]);
    pk.y = pack4_fp8((float)Tt[rd][p4+1], (float)Tt[rd][16+p4+1],
                     (float)Tt[rd][32+p4+1], (float)Tt[rd][48+p4+1]);
    pk.z = pack4_fp8((float)Tt[rd][p4+2], (float)Tt[rd][16+p4+2],
                     (float)Tt[rd][32+p4+2], (float)Tt[rd][48+p4+2]);
    pk.w = pack4_fp8((float)Tt[rd][p4+3], (float)Tt[rd][16+p4+3],
                     (float)Tt[rd][32+p4+3], (float)Tt[rd][48+p4+3]);
    *(i32x4*)(Vt8 + (size_t)(d0 + rd) * 4096 + n0 + part * 16) = pk;
  } else {                             // invt: 16 blocks x 256
    int i = (b - 5632) * 256 + threadIdx.x;
    invt[i] = 1.0f / ((fabsf(T[i]) + 0.1f) * ns[i]);
  }
}

// ------------------------------------------------- main GEMM (C = A . B^T form)
// All-fp8. 128x128 tile, 4 waves 2x2, 4x4 16x16x32 frags/wave.
// K-tile = 128 B. LDS dbuf [buf0|buf1] = 64KB. Tiles [128 r][128 B];
// 16B-chunk o of row r stored at o^(r&7); global_load_lds pre-swizzled src.
// 2-phase: stage(next) BEFORE compute(cur), one barrier/iter (unroll 2).
// EPI 0: N-loop nrep=4; T14 prefetch; epilogue = early-exit exp + direct
//        permuted fp8 stores + Ws[128][36] f32 rowsum slab (buf1).
// __launch_bounds__(256,2): hard 2-blocks/CU floor (VGPR cap 128).
template <int EPI>
__global__ __launch_bounds__(256, 2) void gemm_bt(
    const void* __restrict__ A, const void* __restrict__ B, int Kb, int gx,
    const float* __restrict__ x2, const float* __restrict__ p2,
    const float* __restrict__ invt, u8* __restrict__ Wout,
    float* __restrict__ Wpart,
    const float* __restrict__ rowsum, float* __restrict__ outp) {
  __shared__ __align__(16) char smem[65536];
  char* As = smem;            // +cur: 0 or 32768
  char* Bs = smem + 16384;

  const int nwg = gridDim.x;
  const int sid = (blockIdx.x & 7) * (nwg >> 3) + (blockIdx.x >> 3);
  const int bx = sid % gx, by = sid / gx;

  const int tid = threadIdx.x, lane = tid & 63, w = tid >> 6;
  const int wrow = (w >> 1) * 64, wcol = (w & 1) * 64;
  const int g = lane >> 4, r15 = lane & 15;
  const int m0 = by * 128;

  const char* Ablk = (const char*)A + (size_t)m0 * Kb;

  const int lr = lane >> 3;
  const int lo = (lane & 7) ^ lr;
  const char* aSrc[4]; char* aDst[4]; char* bDst[4];
  int srow[4];
#pragma unroll
  for (int i = 0; i < 4; ++i) {
    int cb  = w * 4 + i;
    srow[i] = cb * 8 + lr;
    aSrc[i] = Ablk + (size_t)srow[i] * Kb + 16 * lo;
    aDst[i] = As + cb * 1024;
    bDst[i] = Bs + cb * 1024;
  }

  int abase[4], asw[4], bbase[4], bsw[4];
#pragma unroll
  for (int mt = 0; mt < 4; ++mt) {
    int r = wrow + mt * 16 + r15;
    abase[mt] = r * 128; asw[mt] = (r & 7) << 4;
    int rb = wcol + mt * 16 + r15;
    bbase[mt] = rb * 128; bsw[mt] = (rb & 7) << 4;
  }

  const int NIT = Kb >> 7;
  constexpr int nrep = (EPI == 0) ? 4 : 1;

  // prologue: stage tile0 of j=0 into buf0
  {
    const char* Bblk0 = (const char*)B + (size_t)(bx * nrep * 128) * Kb;
#pragma unroll
    for (int i = 0; i < 4; ++i) gload16(aSrc[i], aDst[i]);
#pragma unroll
    for (int i = 0; i < 4; ++i)
      gload16(Bblk0 + (size_t)srow[i] * Kb + 16 * lo, bDst[i]);
  }

  for (int j = 0; j < nrep; ++j) {
    const int bxj = bx * nrep + j;
    const int n0 = bxj * 128;
    const char* Bblk = (const char*)B + (size_t)n0 * Kb;
    const char* bSrc[4];
#pragma unroll
    for (int i = 0; i < 4; ++i)
      bSrc[i] = Bblk + (size_t)srow[i] * Kb + 16 * lo;

    // drains tile0 gloads (prologue or T14 prefetch); retires previous
    // epilogue's Ws(buf1) reads before it=0 stages buf1.
    __syncthreads();
    f32x4 acc[4][4] = {};

#pragma unroll 2
    for (int it = 0; it < NIT; ++it) {
      const int cur = (it & 1) << 15;
      const int nxt = cur ^ 32768;
      if (it + 1 < NIT) {                  // issue next-tile loads FIRST
        const int kb1 = (it + 1) << 7;
#pragma unroll
        for (int i = 0; i < 4; ++i) gload16(aSrc[i] + kb1, aDst[i] + nxt);
#pragma unroll
        for (int i = 0; i < 4; ++i) gload16(bSrc[i] + kb1, bDst[i] + nxt);
      }
      const char* As_ = As + cur;
      const char* Bs_ = Bs + cur;
#pragma unroll
      for (int ks = 0; ks < 4; ++ks) {     // 4 k-slices of K=32 fp8
        long aL[4], bL[4];
#pragma unroll
        for (int mt = 0; mt < 4; ++mt)
          aL[mt] = *(const long*)(As_ + (abase[mt] + ((32 * ks + 8 * g) ^ asw[mt])));
#pragma unroll
        for (int nt = 0; nt < 4; ++nt)
          bL[nt] = *(const long*)(Bs_ + (bbase[nt] + ((32 * ks + 8 * g) ^ bsw[nt])));
#pragma unroll
        for (int mt = 0; mt < 4; ++mt)
#pragma unroll
          for (int nt = 0; nt < 4; ++nt)
            acc[mt][nt] = __builtin_amdgcn_mfma_f32_16x16x32_fp8_fp8(aL[mt], bL[nt],
                                                                     acc[mt][nt], 0, 0, 0);
      }
      __syncthreads();
    }
    // after the final barrier all buffer reads are retired.

    if constexpr (EPI == 0) {
      // T14 prefetch: j+1's tile0 into buf0 NOW; epilogue covers latency.
      if (j + 1 < nrep) {
        const char* Bn = (const char*)B + (size_t)((bxj + 1) * 128) * Kb;
#pragma unroll
        for (int i = 0; i < 4; ++i) gload16(aSrc[i], aDst[i]);
#pragma unroll
        for (int i = 0; i < 4; ++i)
          gload16(Bn + (size_t)srow[i] * Kb + 16 * lo, bDst[i]);
      }
      // ---- epilogue: per (mt,reg): 4x d2 (2 fma each) -> EXACT early-exit:
      // d2 >= thr[nt] = (104/invt)^2  =>  expf(-sqrt(d2)*invt) == 0.0f
      // bit-exactly (exp(-104) < min f32 denormal). Wave-uniform __any
      // takes the full sqrt/exp path only if some lane might be nonzero.
      // Stores: ONE permuted nt dword per (mt,reg) (W col' = wcol+4*r15+nt,
      // matching prep_vt's pi). Row-partials to Ws[128][36] f32 (buf1).
      float* Ws = (float*)(smem + 32768);
      float p2v[4], itv[4], thr[4];
#pragma unroll
      for (int nt = 0; nt < 4; ++nt) {
        int n = n0 + wcol + nt * 16 + r15;
        p2v[nt] = p2[n]; itv[nt] = invt[n];
        float lim = 104.0f / itv[nt];
        thr[nt] = lim * lim;
      }
      u8* wbase = Wout + n0 + wcol + 4 * r15;
#pragma unroll
      for (int mt = 0; mt < 4; ++mt) {
#pragma unroll
        for (int reg = 0; reg < 4; ++reg) {
          int ml = wrow + mt * 16 + g * 4 + reg;
          float xx = x2[m0 + ml];
          float d20 = xx + p2v[0] - 2.0f * acc[mt][0][reg];
          float d21 = xx + p2v[1] - 2.0f * acc[mt][1][reg];
          float d22 = xx + p2v[2] - 2.0f * acc[mt][2][reg];
          float d23 = xx + p2v[3] - 2.0f * acc[mt][3][reg];
          int dw = 0;
          float s = 0.0f;
          bool pred = (d20 < thr[0]) || (d21 < thr[1]) ||
                      (d22 < thr[2]) || (d23 < thr[3]);
          if (__any(pred)) {
            float wv0 = __expf(-__builtin_amdgcn_sqrtf(fmaxf(d20, 0.0f)) * itv[0]);
            float wv1 = __expf(-__builtin_amdgcn_sqrtf(fmaxf(d21, 0.0f)) * itv[1]);
            float wv2 = __expf(-__builtin_amdgcn_sqrtf(fmaxf(d22, 0.0f)) * itv[2]);
            float wv3 = __expf(-__builtin_amdgcn_sqrtf(fmaxf(d23, 0.0f)) * itv[3]);
            dw = pack4_fp8(wv0, wv1, wv2, wv3);
            s = wv0 + wv1 + wv2 + wv3;
          }
          __builtin_nontemporal_store(dw, (int*)(wbase + (size_t)(m0 + ml) * 4096));
          Ws[ml * 36 + (w & 1) * 16 + r15] = s;
        }
      }
      __syncthreads();
      {
        int r = tid >> 1, half = tid & 1;
        const float* sp = Ws + r * 36 + half * 16;
        float4 a0 = *(const float4*)(sp);
        float4 a1 = *(const float4*)(sp + 4);
        float4 a2 = *(const float4*)(sp + 8);
        float4 a3 = *(const float4*)(sp + 12);
        float s = a0.x+a0.y+a0.z+a0.w + a1.x+a1.y+a1.z+a1.w
                + a2.x+a2.y+a2.z+a2.w + a3.x+a3.y+a3.z+a3.w;
        Wpart[(size_t)(m0 + r) * 64 + bxj * 2 + half] = s;
      }
    } else {
      // ---- pass B epilogue: O^T transpose via per-wave LDS + normalize
      float* Tb = (float*)(smem) + w * (32 * 66);
      const int dl = lane & 31, half = lane >> 5;
#pragma unroll
      for (int h = 0; h < 2; ++h) {
#pragma unroll
        for (int mh = 0; mh < 2; ++mh) {
          int mt = h * 2 + mh;
#pragma unroll
          for (int nt = 0; nt < 4; ++nt)
#pragma unroll
            for (int reg = 0; reg < 4; ++reg)
              Tb[(mh * 16 + g * 4 + reg) * 66 + nt * 16 + r15] = acc[mt][nt][reg];
        }
#pragma unroll
        for (int rr = 0; rr < 32; ++rr) {
          int mloc = rr * 2 + half;
          float v = Tb[dl * 66 + mloc];
          int mg = n0 + wcol + mloc;
          int dg = m0 + wrow + h * 32 + dl;
          float nrm = 1.0f / (rowsum[mg] + 1e-8f);
          __builtin_nontemporal_store(v * nrm, &outp[(size_t)mg * 512 + dg]);
        }
        __syncthreads();  // Tb reused next h
      }
    }
  }
}

// rowsum[m] = sum of 64 partials
__global__ __launch_bounds__(256) void rowsum_k(const float* __restrict__ Wpart,
                                                float* __restrict__ rowsum) {
  int row  = blockIdx.x * 4 + (threadIdx.x >> 6);
  int lane = threadIdx.x & 63;
  float v = Wpart[(size_t)row * 64 + lane];
  v += __shfl_xor(v, 1);  v += __shfl_xor(v, 2);  v += __shfl_xor(v, 4);
  v += __shfl_xor(v, 8);  v += __shfl_xor(v, 16); v += __shfl_xor(v, 32);
  if (lane == 0) rowsum[row] = v;
}

// ---------------------------------------------------------------------- launch

extern "C" void kernel_launch(void* const* d_in, const int* in_sizes, int n_in,
                              void* d_out, int out_size, void* d_ws, size_t ws_size,
                              hipStream_t stream) {
  const float* x   = (const float*)d_in[0];
  const float* pos = (const float*)d_in[1];
  const float* val = (const float*)d_in[2];
  const float* tmp = (const float*)d_in[3];
  const float* nsc = (const float*)d_in[4];
  float* out = (float*)d_out;

  char* p = (char*)d_ws;
  u8*    X8     = (u8*)p;    p += (size_t)16384 * 512;
  u8*    P8     = (u8*)p;    p += (size_t)4096 * 512;
  u8*    Vt8    = (u8*)p;    p += (size_t)512 * 4096;
  float* x2     = (float*)p; p += (size_t)16384 * 4;
  float* p2     = (float*)p; p += (size_t)4096 * 4;
  float* invt   = (float*)p; p += (size_t)4096 * 4;
  float* rowsum = (float*)p; p += (size_t)16384 * 4;
  float* Wpart  = (float*)p; p += (size_t)16384 * 64 * 4;
  u8*    W8     = (u8*)p;
  size_t fixed  = (size_t)(p - (char*)d_ws);
  size_t wfull  = (size_t)16384 * 4096;   // fp8 W

  if (fixed + wfull > ws_size) return;

  prep_all<<<5648, 256, 0, stream>>>(x, pos, val, tmp, nsc,
                                     X8, P8, Vt8, x2, p2, invt);

  // pass A: Kb = 512 fp8 bytes/row, NIT = 4, N-loop x4 -> grid 8 * 128
  gemm_bt<0><<<8 * 128, 256, 0, stream>>>(
      X8, P8, 512, 8, x2, p2, invt, W8, Wpart, nullptr, nullptr);
  rowsum_k<<<4096, 256, 0, stream>>>(Wpart, rowsum);
  // pass B: Kb = 4096 fp8 bytes/row, NIT = 32
  gemm_bt<1><<<128 * 4, 256, 0, stream>>>(
      Vt8, W8, 4096, 128, nullptr, nullptr, nullptr, nullptr, nullptr,
      rowsum, out);
}

// Round 23
// 96.549 us; speedup vs baseline: 1.4648x; 1.4161x over previous
//
#include <hip/hip_runtime.h>
#include <hip/hip_fp16.h>

// SoftFreezeAttention on MI355X (gfx950).
// out = softmax_rows(exp(-cdist(X,P)/efft)) @ V  with NO max-subtraction
// (reference underflows to 0; computed honestly & exactly).
//
// All-fp8 two-pass pipeline (chunks=1):
//   prep_all: X->X8+x2, P->P8+p2, V->Vt8 (fp8, transposed, n-PERMUTED), invt
//   passA: fp8 GEMM X8.P8^T -> W8 = exp(-dist*invt), N-loop x4, T14
//          epilogue-prefetch, EXACT exp early-exit (expf(-t)==0.0f for
//          t>=104: 6.9e-46 < min denorm 1.4e-45), direct permuted fp8
//          dword nt-stores, Ws rowsum slab, and per-tile-quadrant NONZERO
//          FLAGS (one unconditional byte/wave -> no init needed).
//   rowsum_k; passB: BLOCK-SPARSE fp8 GEMM O^T = Vt8 . W8^T: per k-tile,
//          block-uniform flag==0 => skip staging + all 16 MFMAs (tile
//          contributes exactly 0). Dense fallback = full path (+1 scalar
//          load/branch per iter). Barrier structure identical (no
//          divergence: flags are block-uniform).
//
// History: R11 159.3 -> R14 154.4 -> R17 +guard 154.08 -> R18 +T14 153.9
// -> R19 epilogue diet 140.3 -> R22 exp early-exit 136.7 (passA 74.4,
// MfmaUtil 37.9, VGPR 128@2blk/CU). R23: pass B block-sparse skip driven
// by pass A's exact-zero knowledge (for this data all tiles are zero:
// dist*invt ~ 822 >> 104 by 27 sigma -> passB ~ flag-checks + epilogue).

typedef _Float16 f16;
typedef _Float16 f16x8 __attribute__((ext_vector_type(8)));
typedef float f32x4 __attribute__((ext_vector_type(4)));
typedef int i32x4 __attribute__((ext_vector_type(4)));
typedef unsigned char u8;
typedef unsigned int u32;

#define DEV __device__ __forceinline__

DEV void gload16(const void* g, void* l) {
  __builtin_amdgcn_global_load_lds(
      (const __attribute__((address_space(1))) void*)g,
      (__attribute__((address_space(3))) void*)l, 16, 0, 0);
}

// pack 4 f32 -> 4 fp8 e4m3 bytes (OCP), little-endian [a,b,c,d]
DEV int pack4_fp8(float a, float b, float c, float d) {
  int lo = __builtin_amdgcn_cvt_pk_fp8_f32(a, b, 0, false);
  int hi = __builtin_amdgcn_cvt_pk_fp8_f32(c, d, 0, false);
  return (hi << 16) | (lo & 0xffff);
}

// ---------------------------------------------------------------- fused prep

DEV void row_pack(const float* __restrict__ src, u8* __restrict__ dst,
                  float* __restrict__ sq, int blk) {
  int row  = blk * 4 + (threadIdx.x >> 6);
  int lane = threadIdx.x & 63;
  const float* r = src + (size_t)row * 512 + lane * 8;
  float4 a = *(const float4*)r;
  float4 b = *(const float4*)(r + 4);
  int2 pk;
  pk.x = pack4_fp8(a.x, a.y, a.z, a.w);
  pk.y = pack4_fp8(b.x, b.y, b.z, b.w);
  *(int2*)(dst + (size_t)row * 512 + lane * 8) = pk;
  float ss = a.x*a.x + a.y*a.y + a.z*a.z + a.w*a.w
           + b.x*b.x + b.y*b.y + b.z*b.z + b.w*b.w;
  ss += __shfl_xor(ss, 1);  ss += __shfl_xor(ss, 2);  ss += __shfl_xor(ss, 4);
  ss += __shfl_xor(ss, 8);  ss += __shfl_xor(ss, 16); ss += __shfl_xor(ss, 32);
  if (lane == 0) sq[row] = ss;
}

__global__ __launch_bounds__(256) void prep_all(
    const float* __restrict__ x, const float* __restrict__ pos,
    const float* __restrict__ val, const float* __restrict__ T,
    const float* __restrict__ ns,
    u8* __restrict__ X8, u8* __restrict__ P8, u8* __restrict__ Vt8,
    float* __restrict__ x2, float* __restrict__ p2,
    float* __restrict__ invt) {
  __shared__ f16 Tt[64][72];
  int b = blockIdx.x;
  if (b < 4096) {                      // X: 16384 rows
    row_pack(x, X8, x2, b);
  } else if (b < 5120) {               // P: 4096 rows
    row_pack(pos, P8, p2, b - 4096);
  } else if (b < 5632) {               // Vt: 512 64x64 tiles, pi-permuted n:
    // Vt8[d][blk*64 + r*4 + nt] = fp8(V[blk*64 + nt*16 + r][d])
    int id = b - 5120;
    int n0 = (id & 63) * 64, d0 = (id >> 6) * 64;
    int t = threadIdx.x;
#pragma unroll
    for (int rr = 0; rr < 4; ++rr) {
      int r  = (t >> 4) + rr * 16;
      int cq = t & 15;
      float4 v = *(const float4*)(val + (size_t)(n0 + r) * 512 + d0 + cq * 4);
      Tt[cq*4+0][r] = (f16)v.x; Tt[cq*4+1][r] = (f16)v.y;
      Tt[cq*4+2][r] = (f16)v.z; Tt[cq*4+3][r] = (f16)v.w;
    }
    __syncthreads();
    int rd = t >> 2, part = t & 3;   // dest 16B chunk q = part*16 + j
    int p4 = part * 4;
    i32x4 pk;
    // byte j of chunk: src n-local = (j&3)*16 + p4 + (j>>2)
    pk.x = pack4_fp8((float)Tt[rd][p4+0], (float)Tt[rd][16+p4+0],
                     (float)Tt[rd][32+p4+0], (float)Tt[rd][48+p4+0]);
    pk.y = pack4_fp8((float)Tt[rd][p4+1], (float)Tt[rd][16+p4+1],
                     (float)Tt[rd][32+p4+1], (float)Tt[rd][48+p4+1]);
    pk.z = pack4_fp8((float)Tt[rd][p4+2], (float)Tt[rd][16+p4+2],
                     (float)Tt[rd][32+p4+2], (float)Tt[rd][48+p4+2]);
    pk.w = pack4_fp8((float)Tt[rd][p4+3], (float)Tt[rd][16+p4+3],
                     (float)Tt[rd][32+p4+3], (float)Tt[rd][48+p4+3]);
    *(i32x4*)(Vt8 + (size_t)(d0 + rd) * 4096 + n0 + part * 16) = pk;
  } else {                             // invt: 16 blocks x 256
    int i = (b - 5632) * 256 + threadIdx.x;
    invt[i] = 1.0f / ((fabsf(T[i]) + 0.1f) * ns[i]);
  }
}

// ------------------------------------------------- main GEMM (C = A . B^T form)
// All-fp8. 128x128 tile, 4 waves 2x2, 4x4 16x16x32 frags/wave.
// K-tile = 128 B. LDS dbuf [buf0|buf1] = 64KB. Tiles [128 r][128 B];
// 16B-chunk o of row r stored at o^(r&7); global_load_lds pre-swizzled src.
// 2-phase: stage(next) BEFORE compute(cur), one barrier/iter (unroll 2).
// EPI 0: N-loop nrep=4; T14 prefetch; early-exit exp epilogue + permuted
//        fp8 stores + Ws rowsum slab + nonzero flag byte per wave-quadrant
//        (flag[tile*4+w], tile = by*32+bxj; written unconditionally).
// EPI 1: block-sparse K-loop: tile flag u32==0 -> skip stage+MFMA.
// __launch_bounds__(256,2): hard 2-blocks/CU floor (VGPR cap 128).
template <int EPI>
__global__ __launch_bounds__(256, 2) void gemm_bt(
    const void* __restrict__ A, const void* __restrict__ B, int Kb, int gx,
    const float* __restrict__ x2, const float* __restrict__ p2,
    const float* __restrict__ invt, u8* __restrict__ Wout,
    float* __restrict__ Wpart, void* __restrict__ flagsp,
    const float* __restrict__ rowsum, float* __restrict__ outp) {
  __shared__ __align__(16) char smem[65536];
  char* As = smem;            // +cur: 0 or 32768
  char* Bs = smem + 16384;

  const int nwg = gridDim.x;
  const int sid = (blockIdx.x & 7) * (nwg >> 3) + (blockIdx.x >> 3);
  const int bx = sid % gx, by = sid / gx;

  const int tid = threadIdx.x, lane = tid & 63, w = tid >> 6;
  const int wrow = (w >> 1) * 64, wcol = (w & 1) * 64;
  const int g = lane >> 4, r15 = lane & 15;
  const int m0 = by * 128;

  const char* Ablk = (const char*)A + (size_t)m0 * Kb;

  const int lr = lane >> 3;
  const int lo = (lane & 7) ^ lr;
  const char* aSrc[4]; char* aDst[4]; char* bDst[4];
  int srow[4];
#pragma unroll
  for (int i = 0; i < 4; ++i) {
    int cb  = w * 4 + i;
    srow[i] = cb * 8 + lr;
    aSrc[i] = Ablk + (size_t)srow[i] * Kb + 16 * lo;
    aDst[i] = As + cb * 1024;
    bDst[i] = Bs + cb * 1024;
  }

  int abase[4], asw[4], bbase[4], bsw[4];
#pragma unroll
  for (int mt = 0; mt < 4; ++mt) {
    int r = wrow + mt * 16 + r15;
    abase[mt] = r * 128; asw[mt] = (r & 7) << 4;
    int rb = wcol + mt * 16 + r15;
    bbase[mt] = rb * 128; bsw[mt] = (rb & 7) << 4;
  }

  const int NIT = Kb >> 7;
  constexpr int nrep = (EPI == 0) ? 4 : 1;
  const u32* fl = (const u32*)flagsp;   // pass B: [Wmblock(128)][ntile(32)]

  // prologue: stage tile0 of j=0 into buf0 (pass B: only if tile nonzero)
  {
    bool st0 = true;
    if constexpr (EPI == 1) st0 = fl[bx * 32] != 0;
    if (st0) {
      const char* Bblk0 = (const char*)B + (size_t)(bx * nrep * 128) * Kb;
#pragma unroll
      for (int i = 0; i < 4; ++i) gload16(aSrc[i], aDst[i]);
#pragma unroll
      for (int i = 0; i < 4; ++i)
        gload16(Bblk0 + (size_t)srow[i] * Kb + 16 * lo, bDst[i]);
    }
  }

  for (int j = 0; j < nrep; ++j) {
    const int bxj = bx * nrep + j;
    const int n0 = bxj * 128;
    const char* Bblk = (const char*)B + (size_t)n0 * Kb;
    const char* bSrc[4];
#pragma unroll
    for (int i = 0; i < 4; ++i)
      bSrc[i] = Bblk + (size_t)srow[i] * Kb + 16 * lo;

    // drains tile0 gloads (prologue or T14 prefetch); retires previous
    // epilogue's Ws(buf1) reads before it=0 stages buf1.
    __syncthreads();
    f32x4 acc[4][4] = {};

#pragma unroll 2
    for (int it = 0; it < NIT; ++it) {
      const int cur = (it & 1) << 15;
      const int nxt = cur ^ 32768;
      bool fnx = true, fcu = true;
      if constexpr (EPI == 1) {
        fcu = fl[bx * 32 + it] != 0;
        if (it + 1 < NIT) fnx = fl[bx * 32 + it + 1] != 0;
      }
      if (it + 1 < NIT && fnx) {           // issue next-tile loads FIRST
        const int kb1 = (it + 1) << 7;
#pragma unroll
        for (int i = 0; i < 4; ++i) gload16(aSrc[i] + kb1, aDst[i] + nxt);
#pragma unroll
        for (int i = 0; i < 4; ++i) gload16(bSrc[i] + kb1, bDst[i] + nxt);
      }
      if (fcu) {                            // block-uniform: no divergence
        const char* As_ = As + cur;
        const char* Bs_ = Bs + cur;
#pragma unroll
        for (int ks = 0; ks < 4; ++ks) {    // 4 k-slices of K=32 fp8
          long aL[4], bL[4];
#pragma unroll
          for (int mt = 0; mt < 4; ++mt)
            aL[mt] = *(const long*)(As_ + (abase[mt] + ((32 * ks + 8 * g) ^ asw[mt])));
#pragma unroll
          for (int nt = 0; nt < 4; ++nt)
            bL[nt] = *(const long*)(Bs_ + (bbase[nt] + ((32 * ks + 8 * g) ^ bsw[nt])));
#pragma unroll
          for (int mt = 0; mt < 4; ++mt)
#pragma unroll
            for (int nt = 0; nt < 4; ++nt)
              acc[mt][nt] = __builtin_amdgcn_mfma_f32_16x16x32_fp8_fp8(aL[mt], bL[nt],
                                                                       acc[mt][nt], 0, 0, 0);
        }
      }
      __syncthreads();
    }
    // after the final barrier all buffer reads are retired.

    if constexpr (EPI == 0) {
      // T14 prefetch: j+1's tile0 into buf0 NOW; epilogue covers latency.
      if (j + 1 < nrep) {
        const char* Bn = (const char*)B + (size_t)((bxj + 1) * 128) * Kb;
#pragma unroll
        for (int i = 0; i < 4; ++i) gload16(aSrc[i], aDst[i]);
#pragma unroll
        for (int i = 0; i < 4; ++i)
          gload16(Bn + (size_t)srow[i] * Kb + 16 * lo, bDst[i]);
      }
      // ---- epilogue: EXACT early-exit exp (d2 >= (104/invt)^2 => wv == 0
      // bit-exactly), permuted fp8 dword nt-stores, Ws rowsum slab, and
      // per-wave nonzero flag (unconditional byte store).
      float* Ws = (float*)(smem + 32768);
      float p2v[4], itv[4], thr[4];
#pragma unroll
      for (int nt = 0; nt < 4; ++nt) {
        int n = n0 + wcol + nt * 16 + r15;
        p2v[nt] = p2[n]; itv[nt] = invt[n];
        float lim = 104.0f / itv[nt];
        thr[nt] = lim * lim;
      }
      u8* wbase = Wout + n0 + wcol + 4 * r15;
      bool tnz = false;
#pragma unroll
      for (int mt = 0; mt < 4; ++mt) {
#pragma unroll
        for (int reg = 0; reg < 4; ++reg) {
          int ml = wrow + mt * 16 + g * 4 + reg;
          float xx = x2[m0 + ml];
          float d20 = xx + p2v[0] - 2.0f * acc[mt][0][reg];
          float d21 = xx + p2v[1] - 2.0f * acc[mt][1][reg];
          float d22 = xx + p2v[2] - 2.0f * acc[mt][2][reg];
          float d23 = xx + p2v[3] - 2.0f * acc[mt][3][reg];
          int dw = 0;
          float s = 0.0f;
          bool pred = (d20 < thr[0]) || (d21 < thr[1]) ||
                      (d22 < thr[2]) || (d23 < thr[3]);
          if (__any(pred)) {
            float wv0 = __expf(-__builtin_amdgcn_sqrtf(fmaxf(d20, 0.0f)) * itv[0]);
            float wv1 = __expf(-__builtin_amdgcn_sqrtf(fmaxf(d21, 0.0f)) * itv[1]);
            float wv2 = __expf(-__builtin_amdgcn_sqrtf(fmaxf(d22, 0.0f)) * itv[2]);
            float wv3 = __expf(-__builtin_amdgcn_sqrtf(fmaxf(d23, 0.0f)) * itv[3]);
            dw = pack4_fp8(wv0, wv1, wv2, wv3);
            s = wv0 + wv1 + wv2 + wv3;
            tnz = tnz || (dw != 0);
          }
          __builtin_nontemporal_store(dw, (int*)(wbase + (size_t)(m0 + ml) * 4096));
          Ws[ml * 36 + (w & 1) * 16 + r15] = s;
        }
      }
      // nonzero flag for this wave's 64x64 quadrant of tile (by,bxj):
      // pass B reads the tile's u32 (4 bytes = 4 waves); always written.
      {
        bool wnz = __any(tnz);
        if (lane == 0)
          ((u8*)flagsp)[(size_t)(by * 32 + bxj) * 4 + w] = wnz ? 1 : 0;
      }
      __syncthreads();
      {
        int r = tid >> 1, half = tid & 1;
        const float* sp = Ws + r * 36 + half * 16;
        float4 a0 = *(const float4*)(sp);
        float4 a1 = *(const float4*)(sp + 4);
        float4 a2 = *(const float4*)(sp + 8);
        float4 a3 = *(const float4*)(sp + 12);
        float s = a0.x+a0.y+a0.z+a0.w + a1.x+a1.y+a1.z+a1.w
                + a2.x+a2.y+a2.z+a2.w + a3.x+a3.y+a3.z+a3.w;
        Wpart[(size_t)(m0 + r) * 64 + bxj * 2 + half] = s;
      }
    } else {
      // ---- pass B epilogue: O^T transpose via per-wave LDS + normalize
      float* Tb = (float*)(smem) + w * (32 * 66);
      const int dl = lane & 31, half = lane >> 5;
#pragma unroll
      for (int h = 0; h < 2; ++h) {
#pragma unroll
        for (int mh = 0; mh < 2; ++mh) {
          int mt = h * 2 + mh;
#pragma unroll
          for (int nt = 0; nt < 4; ++nt)
#pragma unroll
            for (int reg = 0; reg < 4; ++reg)
              Tb[(mh * 16 + g * 4 + reg) * 66 + nt * 16 + r15] = acc[mt][nt][reg];
        }
#pragma unroll
        for (int rr = 0; rr < 32; ++rr) {
          int mloc = rr * 2 + half;
          float v = Tb[dl * 66 + mloc];
          int mg = n0 + wcol + mloc;
          int dg = m0 + wrow + h * 32 + dl;
          float nrm = 1.0f / (rowsum[mg] + 1e-8f);
          __builtin_nontemporal_store(v * nrm, &outp[(size_t)mg * 512 + dg]);
        }
        __syncthreads();  // Tb reused next h
      }
    }
  }
}

// rowsum[m] = sum of 64 partials
__global__ __launch_bounds__(256) void rowsum_k(const float* __restrict__ Wpart,
                                                float* __restrict__ rowsum) {
  int row  = blockIdx.x * 4 + (threadIdx.x >> 6);
  int lane = threadIdx.x & 63;
  float v = Wpart[(size_t)row * 64 + lane];
  v += __shfl_xor(v, 1);  v += __shfl_xor(v, 2);  v += __shfl_xor(v, 4);
  v += __shfl_xor(v, 8);  v += __shfl_xor(v, 16); v += __shfl_xor(v, 32);
  if (lane == 0) rowsum[row] = v;
}

// ---------------------------------------------------------------------- launch

extern "C" void kernel_launch(void* const* d_in, const int* in_sizes, int n_in,
                              void* d_out, int out_size, void* d_ws, size_t ws_size,
                              hipStream_t stream) {
  const float* x   = (const float*)d_in[0];
  const float* pos = (const float*)d_in[1];
  const float* val = (const float*)d_in[2];
  const float* tmp = (const float*)d_in[3];
  const float* nsc = (const float*)d_in[4];
  float* out = (float*)d_out;

  char* p = (char*)d_ws;
  u8*    X8     = (u8*)p;    p += (size_t)16384 * 512;
  u8*    P8     = (u8*)p;    p += (size_t)4096 * 512;
  u8*    Vt8    = (u8*)p;    p += (size_t)512 * 4096;
  float* x2     = (float*)p; p += (size_t)16384 * 4;
  float* p2     = (float*)p; p += (size_t)4096 * 4;
  float* invt   = (float*)p; p += (size_t)4096 * 4;
  float* rowsum = (float*)p; p += (size_t)16384 * 4;
  float* Wpart  = (float*)p; p += (size_t)16384 * 64 * 4;
  void*  flags  = (void*)p;  p += (size_t)128 * 32 * 4;   // tile nz flags
  u8*    W8     = (u8*)p;
  size_t fixed  = (size_t)(p - (char*)d_ws);
  size_t wfull  = (size_t)16384 * 4096;   // fp8 W

  if (fixed + wfull > ws_size) return;

  prep_all<<<5648, 256, 0, stream>>>(x, pos, val, tmp, nsc,
                                     X8, P8, Vt8, x2, p2, invt);

  // pass A: Kb = 512 fp8 bytes/row, NIT = 4, N-loop x4 -> grid 8 * 128
  gemm_bt<0><<<8 * 128, 256, 0, stream>>>(
      X8, P8, 512, 8, x2, p2, invt, W8, Wpart, flags, nullptr, nullptr);
  rowsum_k<<<4096, 256, 0, stream>>>(Wpart, rowsum);
  // pass B: Kb = 4096 fp8 bytes/row, NIT = 32, block-sparse over flags
  gemm_bt<1><<<128 * 4, 256, 0, stream>>>(
      Vt8, W8, 4096, 128, nullptr, nullptr, nullptr, nullptr, nullptr, flags,
      rowsum, out);
}

// Round 24
// 40.164 us; speedup vs baseline: 3.5212x; 2.4039x over previous
//
#include <hip/hip_runtime.h>
#include <hip/hip_fp16.h>

// SoftFreezeAttention on MI355X (gfx950).
// out = softmax_rows(exp(-cdist(X,P)/efft)) @ V  with NO max-subtraction.
//
// All-fp8 two-pass pipeline with EXACT zero-propagation both ways:
//   prep_all: X->X8+x2, P->P8+p2, V->Vt8 (fp8, transposed, n-PERMUTED), invt
//   bounds_k: per-m-tile [min,max] of |x|; per-n-tile band
//             [min(|p|-r), max(|p|+r)], r = 112/invt.
//   passA: per 128x128 tile: TRIANGLE-INEQUALITY SKIP — dist >= ||x|-|p||,
//          so disjoint intervals => every w underflows to exact 0 (margin:
//          112 vs the 104 underflow bound; adversarial residual <= 4e-38
//          << 0.02). Skip path: flag=0 + Wpart=0, no GEMM/staging/barriers
//          (block-uniform). Dense path: fp8 GEMM + early-exit exp epilogue
//          (expf(-t)==0.0f for t>=104) + permuted fp8 nt-stores + flags.
//   rowsum_k; passB: BLOCK-SPARSE fp8 GEMM O^T = Vt8 . W8^T over flags
//          (flag==0 => skip staging + MFMAs), transpose + normalize.
//
// History: R11 159.3 -> R14 154.4 -> R19 epilogue diet 140.3 -> R22 exp
// early-exit 136.7 -> R23 passB block-sparse 96.5 (passB 54->9us). R24:
// same exactness argument applied BEFORE the QK GEMM via norm bounds.

typedef _Float16 f16;
typedef _Float16 f16x8 __attribute__((ext_vector_type(8)));
typedef float f32x4 __attribute__((ext_vector_type(4)));
typedef int i32x4 __attribute__((ext_vector_type(4)));
typedef unsigned char u8;
typedef unsigned int u32;

#define DEV __device__ __forceinline__

DEV void gload16(const void* g, void* l) {
  __builtin_amdgcn_global_load_lds(
      (const __attribute__((address_space(1))) void*)g,
      (__attribute__((address_space(3))) void*)l, 16, 0, 0);
}

// pack 4 f32 -> 4 fp8 e4m3 bytes (OCP), little-endian [a,b,c,d]
DEV int pack4_fp8(float a, float b, float c, float d) {
  int lo = __builtin_amdgcn_cvt_pk_fp8_f32(a, b, 0, false);
  int hi = __builtin_amdgcn_cvt_pk_fp8_f32(c, d, 0, false);
  return (hi << 16) | (lo & 0xffff);
}

// ---------------------------------------------------------------- fused prep

DEV void row_pack(const float* __restrict__ src, u8* __restrict__ dst,
                  float* __restrict__ sq, int blk) {
  int row  = blk * 4 + (threadIdx.x >> 6);
  int lane = threadIdx.x & 63;
  const float* r = src + (size_t)row * 512 + lane * 8;
  float4 a = *(const float4*)r;
  float4 b = *(const float4*)(r + 4);
  int2 pk;
  pk.x = pack4_fp8(a.x, a.y, a.z, a.w);
  pk.y = pack4_fp8(b.x, b.y, b.z, b.w);
  *(int2*)(dst + (size_t)row * 512 + lane * 8) = pk;
  float ss = a.x*a.x + a.y*a.y + a.z*a.z + a.w*a.w
           + b.x*b.x + b.y*b.y + b.z*b.z + b.w*b.w;
  ss += __shfl_xor(ss, 1);  ss += __shfl_xor(ss, 2);  ss += __shfl_xor(ss, 4);
  ss += __shfl_xor(ss, 8);  ss += __shfl_xor(ss, 16); ss += __shfl_xor(ss, 32);
  if (lane == 0) sq[row] = ss;
}

__global__ __launch_bounds__(256) void prep_all(
    const float* __restrict__ x, const float* __restrict__ pos,
    const float* __restrict__ val, const float* __restrict__ T,
    const float* __restrict__ ns,
    u8* __restrict__ X8, u8* __restrict__ P8, u8* __restrict__ Vt8,
    float* __restrict__ x2, float* __restrict__ p2,
    float* __restrict__ invt) {
  __shared__ f16 Tt[64][72];
  int b = blockIdx.x;
  if (b < 4096) {                      // X: 16384 rows
    row_pack(x, X8, x2, b);
  } else if (b < 5120) {               // P: 4096 rows
    row_pack(pos, P8, p2, b - 4096);
  } else if (b < 5632) {               // Vt: 512 64x64 tiles, pi-permuted n
    int id = b - 5120;
    int n0 = (id & 63) * 64, d0 = (id >> 6) * 64;
    int t = threadIdx.x;
#pragma unroll
    for (int rr = 0; rr < 4; ++rr) {
      int r  = (t >> 4) + rr * 16;
      int cq = t & 15;
      float4 v = *(const float4*)(val + (size_t)(n0 + r) * 512 + d0 + cq * 4);
      Tt[cq*4+0][r] = (f16)v.x; Tt[cq*4+1][r] = (f16)v.y;
      Tt[cq*4+2][r] = (f16)v.z; Tt[cq*4+3][r] = (f16)v.w;
    }
    __syncthreads();
    int rd = t >> 2, part = t & 3;
    int p4 = part * 4;
    i32x4 pk;
    pk.x = pack4_fp8((float)Tt[rd][p4+0], (float)Tt[rd][16+p4+0],
                     (float)Tt[rd][32+p4+0], (float)Tt[rd][48+p4+0]);
    pk.y = pack4_fp8((float)Tt[rd][p4+1], (float)Tt[rd][16+p4+1],
                     (float)Tt[rd][32+p4+1], (float)Tt[rd][48+p4+1]);
    pk.z = pack4_fp8((float)Tt[rd][p4+2], (float)Tt[rd][16+p4+2],
                     (float)Tt[rd][32+p4+2], (float)Tt[rd][48+p4+2]);
    pk.w = pack4_fp8((float)Tt[rd][p4+3], (float)Tt[rd][16+p4+3],
                     (float)Tt[rd][32+p4+3], (float)Tt[rd][48+p4+3]);
    *(i32x4*)(Vt8 + (size_t)(d0 + rd) * 4096 + n0 + part * 16) = pk;
  } else {                             // invt: 16 blocks x 256
    int i = (b - 5632) * 256 + threadIdx.x;
    invt[i] = 1.0f / ((fabsf(T[i]) + 0.1f) * ns[i]);
  }
}

// ------------------------------------ per-tile norm bounds (after prep_all)
// blocks 0..127: m-tile i -> xb[i*2]=min|x|, xb[i*2+1]=max|x| (128 rows).
// blocks 128..159: n-tile i -> nb[i*2]=min(|p|-r), nb[i*2+1]=max(|p|+r),
//                  r = 112/invt (8-unit margin over the 104 underflow bound).
__global__ __launch_bounds__(64) void bounds_k(
    const float* __restrict__ x2, const float* __restrict__ p2,
    const float* __restrict__ invt, float* __restrict__ xb,
    float* __restrict__ nb) {
  int t = threadIdx.x;
  float lo, hi;
  if (blockIdx.x < 128) {
    int base = blockIdx.x * 128;
    float a = __builtin_amdgcn_sqrtf(x2[base + t]);
    float b = __builtin_amdgcn_sqrtf(x2[base + 64 + t]);
    lo = fminf(a, b); hi = fmaxf(a, b);
  } else {
    int base = (blockIdx.x - 128) * 128;
    float pa = __builtin_amdgcn_sqrtf(p2[base + t]);
    float pb = __builtin_amdgcn_sqrtf(p2[base + 64 + t]);
    float ra = 112.0f / invt[base + t];
    float rb = 112.0f / invt[base + 64 + t];
    lo = fminf(pa - ra, pb - rb); hi = fmaxf(pa + ra, pb + rb);
  }
#pragma unroll
  for (int s = 1; s < 64; s <<= 1) {
    lo = fminf(lo, __shfl_xor(lo, s));
    hi = fmaxf(hi, __shfl_xor(hi, s));
  }
  if (t == 0) {
    if (blockIdx.x < 128) { xb[blockIdx.x*2] = lo; xb[blockIdx.x*2+1] = hi; }
    else { int i = blockIdx.x - 128; nb[i*2] = lo; nb[i*2+1] = hi; }
  }
}

// ------------------------------------------------- main GEMM (C = A . B^T form)
// All-fp8. 128x128 tile, 4 waves 2x2, 4x4 16x16x32 frags/wave.
// K-tile = 128 B. LDS dbuf [buf0|buf1] = 64KB. Tiles [128 r][128 B];
// 16B-chunk o of row r stored at o^(r&7); global_load_lds pre-swizzled src.
// EPI 0: N-loop nrep=4 with per-tile TRIANGLE-INEQUALITY SKIP (block-
//        uniform; skip = flag0+Wpart0 writes only). Dense: stage tile0 at
//        j-top, 2-phase K-loop, early-exit exp epilogue + permuted fp8
//        nt-stores + Ws rowsum slab + nonzero flags.
// EPI 1: block-sparse K-loop over flags (R23, unchanged).
// __launch_bounds__(256,2): hard 2-blocks/CU floor (VGPR cap 128).
template <int EPI>
__global__ __launch_bounds__(256, 2) void gemm_bt(
    const void* __restrict__ A, const void* __restrict__ B, int Kb, int gx,
    const float* __restrict__ x2, const float* __restrict__ p2,
    const float* __restrict__ invt, u8* __restrict__ Wout,
    float* __restrict__ Wpart, void* __restrict__ flagsp,
    const float* __restrict__ xb, const float* __restrict__ nb,
    const float* __restrict__ rowsum, float* __restrict__ outp) {
  __shared__ __align__(16) char smem[65536];
  char* As = smem;            // +cur: 0 or 32768
  char* Bs = smem + 16384;

  const int nwg = gridDim.x;
  const int sid = (blockIdx.x & 7) * (nwg >> 3) + (blockIdx.x >> 3);
  const int bx = sid % gx, by = sid / gx;

  const int tid = threadIdx.x, lane = tid & 63, w = tid >> 6;
  const int wrow = (w >> 1) * 64, wcol = (w & 1) * 64;
  const int g = lane >> 4, r15 = lane & 15;
  const int m0 = by * 128;

  const char* Ablk = (const char*)A + (size_t)m0 * Kb;

  const int lr = lane >> 3;
  const int lo = (lane & 7) ^ lr;
  const char* aSrc[4]; char* aDst[4]; char* bDst[4];
  int srow[4];
#pragma unroll
  for (int i = 0; i < 4; ++i) {
    int cb  = w * 4 + i;
    srow[i] = cb * 8 + lr;
    aSrc[i] = Ablk + (size_t)srow[i] * Kb + 16 * lo;
    aDst[i] = As + cb * 1024;
    bDst[i] = Bs + cb * 1024;
  }

  int abase[4], asw[4], bbase[4], bsw[4];
#pragma unroll
  for (int mt = 0; mt < 4; ++mt) {
    int r = wrow + mt * 16 + r15;
    abase[mt] = r * 128; asw[mt] = (r & 7) << 4;
    int rb = wcol + mt * 16 + r15;
    bbase[mt] = rb * 128; bsw[mt] = (rb & 7) << 4;
  }

  const int NIT = Kb >> 7;
  constexpr int nrep = (EPI == 0) ? 4 : 1;
  const u32* fl = (const u32*)flagsp;   // pass B: [Wmblock(128)][ntile(32)]

  // pass B prologue: stage tile0 only if nonzero (R23)
  if constexpr (EPI == 1) {
    if (fl[bx * 32] != 0) {
      const char* Bblk0 = (const char*)B + (size_t)(bx * nrep * 128) * Kb;
#pragma unroll
      for (int i = 0; i < 4; ++i) gload16(aSrc[i], aDst[i]);
#pragma unroll
      for (int i = 0; i < 4; ++i)
        gload16(Bblk0 + (size_t)srow[i] * Kb + 16 * lo, bDst[i]);
    }
  }

  float xlo, xhi;
  if constexpr (EPI == 0) { xlo = xb[by * 2]; xhi = xb[by * 2 + 1]; }

  for (int j = 0; j < nrep; ++j) {
    const int bxj = bx * nrep + j;
    const int n0 = bxj * 128;

    if constexpr (EPI == 0) {
      // ---- triangle-inequality tile skip (block-uniform, no divergence):
      // dist(x,p) >= ||x|-|p||; if [xlo,xhi] misses the band
      // [min(|p|-112/invt), max(|p|+112/invt)], every w in the tile
      // underflows to exact 0 -> no GEMM, no W writes, flag=0, Wpart=0.
      float blo = nb[bxj * 2], bhi = nb[bxj * 2 + 1];
      if (xhi < blo || xlo > bhi) {
        if (lane == 0)
          ((u8*)flagsp)[(size_t)(by * 32 + bxj) * 4 + w] = 0;
        int r = tid >> 1, half = tid & 1;
        Wpart[(size_t)(m0 + r) * 64 + bxj * 2 + half] = 0.0f;
        continue;                      // uniform: no barriers skipped
      }
    }

    const char* Bblk = (const char*)B + (size_t)n0 * Kb;
    const char* bSrc[4];
#pragma unroll
    for (int i = 0; i < 4; ++i)
      bSrc[i] = Bblk + (size_t)srow[i] * Kb + 16 * lo;

    // retire previous epilogue's Ws(buf1)/frag reads before restaging
    __syncthreads();
    if constexpr (EPI == 0) {
      // dense path stages its own tile0 (no cross-j prefetch with skips)
#pragma unroll
      for (int i = 0; i < 4; ++i) gload16(aSrc[i], aDst[i]);
#pragma unroll
      for (int i = 0; i < 4; ++i) gload16(bSrc[i], bDst[i]);
      __syncthreads();
    }
    f32x4 acc[4][4] = {};

#pragma unroll 2
    for (int it = 0; it < NIT; ++it) {
      const int cur = (it & 1) << 15;
      const int nxt = cur ^ 32768;
      bool fnx = true, fcu = true;
      if constexpr (EPI == 1) {
        fcu = fl[bx * 32 + it] != 0;
        if (it + 1 < NIT) fnx = fl[bx * 32 + it + 1] != 0;
      }
      if (it + 1 < NIT && fnx) {           // issue next-tile loads FIRST
        const int kb1 = (it + 1) << 7;
#pragma unroll
        for (int i = 0; i < 4; ++i) gload16(aSrc[i] + kb1, aDst[i] + nxt);
#pragma unroll
        for (int i = 0; i < 4; ++i) gload16(bSrc[i] + kb1, bDst[i] + nxt);
      }
      if (fcu) {                            // block-uniform: no divergence
        const char* As_ = As + cur;
        const char* Bs_ = Bs + cur;
#pragma unroll
        for (int ks = 0; ks < 4; ++ks) {    // 4 k-slices of K=32 fp8
          long aL[4], bL[4];
#pragma unroll
          for (int mt = 0; mt < 4; ++mt)
            aL[mt] = *(const long*)(As_ + (abase[mt] + ((32 * ks + 8 * g) ^ asw[mt])));
#pragma unroll
          for (int nt = 0; nt < 4; ++nt)
            bL[nt] = *(const long*)(Bs_ + (bbase[nt] + ((32 * ks + 8 * g) ^ bsw[nt])));
#pragma unroll
          for (int mt = 0; mt < 4; ++mt)
#pragma unroll
            for (int nt = 0; nt < 4; ++nt)
              acc[mt][nt] = __builtin_amdgcn_mfma_f32_16x16x32_fp8_fp8(aL[mt], bL[nt],
                                                                       acc[mt][nt], 0, 0, 0);
        }
      }
      __syncthreads();
    }
    // after the final barrier all buffer reads are retired.

    if constexpr (EPI == 0) {
      // ---- dense epilogue: EXACT early-exit exp (d2 >= (104/invt)^2 =>
      // wv == 0 bit-exactly), permuted fp8 dword nt-stores, Ws rowsum
      // slab, per-wave nonzero flag (unconditional byte store).
      float* Ws = (float*)(smem + 32768);
      float p2v[4], itv[4], thr[4];
#pragma unroll
      for (int nt = 0; nt < 4; ++nt) {
        int n = n0 + wcol + nt * 16 + r15;
        p2v[nt] = p2[n]; itv[nt] = invt[n];
        float lim = 104.0f / itv[nt];
        thr[nt] = lim * lim;
      }
      u8* wbase = Wout + n0 + wcol + 4 * r15;
      bool tnz = false;
#pragma unroll
      for (int mt = 0; mt < 4; ++mt) {
#pragma unroll
        for (int reg = 0; reg < 4; ++reg) {
          int ml = wrow + mt * 16 + g * 4 + reg;
          float xx = x2[m0 + ml];
          float d20 = xx + p2v[0] - 2.0f * acc[mt][0][reg];
          float d21 = xx + p2v[1] - 2.0f * acc[mt][1][reg];
          float d22 = xx + p2v[2] - 2.0f * acc[mt][2][reg];
          float d23 = xx + p2v[3] - 2.0f * acc[mt][3][reg];
          int dw = 0;
          float s = 0.0f;
          bool pred = (d20 < thr[0]) || (d21 < thr[1]) ||
                      (d22 < thr[2]) || (d23 < thr[3]);
          if (__any(pred)) {
            float wv0 = __expf(-__builtin_amdgcn_sqrtf(fmaxf(d20, 0.0f)) * itv[0]);
            float wv1 = __expf(-__builtin_amdgcn_sqrtf(fmaxf(d21, 0.0f)) * itv[1]);
            float wv2 = __expf(-__builtin_amdgcn_sqrtf(fmaxf(d22, 0.0f)) * itv[2]);
            float wv3 = __expf(-__builtin_amdgcn_sqrtf(fmaxf(d23, 0.0f)) * itv[3]);
            dw = pack4_fp8(wv0, wv1, wv2, wv3);
            s = wv0 + wv1 + wv2 + wv3;
            tnz = tnz || (dw != 0);
          }
          __builtin_nontemporal_store(dw, (int*)(wbase + (size_t)(m0 + ml) * 4096));
          Ws[ml * 36 + (w & 1) * 16 + r15] = s;
        }
      }
      {
        bool wnz = __any(tnz);
        if (lane == 0)
          ((u8*)flagsp)[(size_t)(by * 32 + bxj) * 4 + w] = wnz ? 1 : 0;
      }
      __syncthreads();
      {
        int r = tid >> 1, half = tid & 1;
        const float* sp = Ws + r * 36 + half * 16;
        float4 a0 = *(const float4*)(sp);
        float4 a1 = *(const float4*)(sp + 4);
        float4 a2 = *(const float4*)(sp + 8);
        float4 a3 = *(const float4*)(sp + 12);
        float s = a0.x+a0.y+a0.z+a0.w + a1.x+a1.y+a1.z+a1.w
                + a2.x+a2.y+a2.z+a2.w + a3.x+a3.y+a3.z+a3.w;
        Wpart[(size_t)(m0 + r) * 64 + bxj * 2 + half] = s;
      }
    } else {
      // ---- pass B epilogue: O^T transpose via per-wave LDS + normalize
      float* Tb = (float*)(smem) + w * (32 * 66);
      const int dl = lane & 31, half = lane >> 5;
#pragma unroll
      for (int h = 0; h < 2; ++h) {
#pragma unroll
        for (int mh = 0; mh < 2; ++mh) {
          int mt = h * 2 + mh;
#pragma unroll
          for (int nt = 0; nt < 4; ++nt)
#pragma unroll
            for (int reg = 0; reg < 4; ++reg)
              Tb[(mh * 16 + g * 4 + reg) * 66 + nt * 16 + r15] = acc[mt][nt][reg];
        }
#pragma unroll
        for (int rr = 0; rr < 32; ++rr) {
          int mloc = rr * 2 + half;
          float v = Tb[dl * 66 + mloc];
          int mg = n0 + wcol + mloc;
          int dg = m0 + wrow + h * 32 + dl;
          float nrm = 1.0f / (rowsum[mg] + 1e-8f);
          __builtin_nontemporal_store(v * nrm, &outp[(size_t)mg * 512 + dg]);
        }
        __syncthreads();  // Tb reused next h
      }
    }
  }
}

// rowsum[m] = sum of 64 partials
__global__ __launch_bounds__(256) void rowsum_k(const float* __restrict__ Wpart,
                                                float* __restrict__ rowsum) {
  int row  = blockIdx.x * 4 + (threadIdx.x >> 6);
  int lane = threadIdx.x & 63;
  float v = Wpart[(size_t)row * 64 + lane];
  v += __shfl_xor(v, 1);  v += __shfl_xor(v, 2);  v += __shfl_xor(v, 4);
  v += __shfl_xor(v, 8);  v += __shfl_xor(v, 16); v += __shfl_xor(v, 32);
  if (lane == 0) rowsum[row] = v;
}

// ---------------------------------------------------------------------- launch

extern "C" void kernel_launch(void* const* d_in, const int* in_sizes, int n_in,
                              void* d_out, int out_size, void* d_ws, size_t ws_size,
                              hipStream_t stream) {
  const float* x   = (const float*)d_in[0];
  const float* pos = (const float*)d_in[1];
  const float* val = (const float*)d_in[2];
  const float* tmp = (const float*)d_in[3];
  const float* nsc = (const float*)d_in[4];
  float* out = (float*)d_out;

  char* p = (char*)d_ws;
  u8*    X8     = (u8*)p;    p += (size_t)16384 * 512;
  u8*    P8     = (u8*)p;    p += (size_t)4096 * 512;
  u8*    Vt8    = (u8*)p;    p += (size_t)512 * 4096;
  float* x2     = (float*)p; p += (size_t)16384 * 4;
  float* p2     = (float*)p; p += (size_t)4096 * 4;
  float* invt   = (float*)p; p += (size_t)4096 * 4;
  float* rowsum = (float*)p; p += (size_t)16384 * 4;
  float* Wpart  = (float*)p; p += (size_t)16384 * 64 * 4;
  void*  flags  = (void*)p;  p += (size_t)128 * 32 * 4;   // tile nz flags
  float* xb     = (float*)p; p += (size_t)128 * 2 * 4;    // m-tile |x| bounds
  float* nb     = (float*)p; p += (size_t)32 * 2 * 4;     // n-tile bands
  u8*    W8     = (u8*)p;
  size_t fixed  = (size_t)(p - (char*)d_ws);
  size_t wfull  = (size_t)16384 * 4096;   // fp8 W

  if (fixed + wfull > ws_size) return;

  prep_all<<<5648, 256, 0, stream>>>(x, pos, val, tmp, nsc,
                                     X8, P8, Vt8, x2, p2, invt);
  bounds_k<<<160, 64, 0, stream>>>(x2, p2, invt, xb, nb);

  // pass A: Kb = 512 fp8 bytes/row, NIT = 4, N-loop x4 -> grid 8 * 128
  gemm_bt<0><<<8 * 128, 256, 0, stream>>>(
      X8, P8, 512, 8, x2, p2, invt, W8, Wpart, flags, xb, nb,
      nullptr, nullptr);
  rowsum_k<<<4096, 256, 0, stream>>>(Wpart, rowsum);
  // pass B: Kb = 4096 fp8 bytes/row, NIT = 32, block-sparse over flags
  gemm_bt<1><<<128 * 4, 256, 0, stream>>>(
      Vt8, W8, 4096, 128, nullptr, nullptr, nullptr, nullptr, nullptr, flags,
      nullptr, nullptr, rowsum, out);
}

// Round 25
// 38.610 us; speedup vs baseline: 3.6629x; 1.0402x over previous
//
#include <hip/hip_runtime.h>
#include <hip/hip_fp16.h>

// SoftFreezeAttention on MI355X (gfx950).
// out = softmax_rows(exp(-cdist(X,P)/efft)) @ V  with NO max-subtraction.
//
// All-fp8 two-pass pipeline with EXACT zero-propagation both ways:
//   prep_all: X->X8+x2, P->P8+p2, V->Vt8 (fp8, transposed, n-PERMUTED), invt
//   bounds_k: per-m-tile [min,max] of |x|; per-n-tile band
//             [min(|p|-r), max(|p|+r)], r = 112/invt.
//   passA: per 128x128 tile TRIANGLE-INEQUALITY SKIP (dist >= ||x|-|p||;
//          disjoint intervals => every w underflows to exact 0; margin 112
//          vs the 104 underflow bound). Dense path: fp8 GEMM + early-exit
//          exp epilogue + permuted fp8 nt-stores + nonzero flags + Wpart.
//   passB: rowsum folded in (from Wpart -> LDS rsum slab, rowsum_k kernel
//          dropped); ALL-ZERO FAST PATH: if all 32 tile flags are 0, skip
//          the whole K-loop incl. barriers (block-uniform). Dense fallback:
//          block-sparse K-loop over flags (R23). Transpose + normalize.
//
// History: R11 159.3 -> R19 140.3 -> R22 exp early-exit 136.7 -> R23
// passB block-sparse 96.5 -> R24 passA triangle skip 40.2 (absmax 0).
// R25: launch consolidation (5->4 kernels) + passB barrier-free fast path.

typedef _Float16 f16;
typedef _Float16 f16x8 __attribute__((ext_vector_type(8)));
typedef float f32x4 __attribute__((ext_vector_type(4)));
typedef int i32x4 __attribute__((ext_vector_type(4)));
typedef unsigned char u8;
typedef unsigned int u32;

#define DEV __device__ __forceinline__

DEV void gload16(const void* g, void* l) {
  __builtin_amdgcn_global_load_lds(
      (const __attribute__((address_space(1))) void*)g,
      (__attribute__((address_space(3))) void*)l, 16, 0, 0);
}

// pack 4 f32 -> 4 fp8 e4m3 bytes (OCP), little-endian [a,b,c,d]
DEV int pack4_fp8(float a, float b, float c, float d) {
  int lo = __builtin_amdgcn_cvt_pk_fp8_f32(a, b, 0, false);
  int hi = __builtin_amdgcn_cvt_pk_fp8_f32(c, d, 0, false);
  return (hi << 16) | (lo & 0xffff);
}

// ---------------------------------------------------------------- fused prep

DEV void row_pack(const float* __restrict__ src, u8* __restrict__ dst,
                  float* __restrict__ sq, int blk) {
  int row  = blk * 4 + (threadIdx.x >> 6);
  int lane = threadIdx.x & 63;
  const float* r = src + (size_t)row * 512 + lane * 8;
  float4 a = *(const float4*)r;
  float4 b = *(const float4*)(r + 4);
  int2 pk;
  pk.x = pack4_fp8(a.x, a.y, a.z, a.w);
  pk.y = pack4_fp8(b.x, b.y, b.z, b.w);
  *(int2*)(dst + (size_t)row * 512 + lane * 8) = pk;
  float ss = a.x*a.x + a.y*a.y + a.z*a.z + a.w*a.w
           + b.x*b.x + b.y*b.y + b.z*b.z + b.w*b.w;
  ss += __shfl_xor(ss, 1);  ss += __shfl_xor(ss, 2);  ss += __shfl_xor(ss, 4);
  ss += __shfl_xor(ss, 8);  ss += __shfl_xor(ss, 16); ss += __shfl_xor(ss, 32);
  if (lane == 0) sq[row] = ss;
}

__global__ __launch_bounds__(256) void prep_all(
    const float* __restrict__ x, const float* __restrict__ pos,
    const float* __restrict__ val, const float* __restrict__ T,
    const float* __restrict__ ns,
    u8* __restrict__ X8, u8* __restrict__ P8, u8* __restrict__ Vt8,
    float* __restrict__ x2, float* __restrict__ p2,
    float* __restrict__ invt) {
  __shared__ f16 Tt[64][72];
  int b = blockIdx.x;
  if (b < 4096) {                      // X: 16384 rows
    row_pack(x, X8, x2, b);
  } else if (b < 5120) {               // P: 4096 rows
    row_pack(pos, P8, p2, b - 4096);
  } else if (b < 5632) {               // Vt: 512 64x64 tiles, pi-permuted n
    int id = b - 5120;
    int n0 = (id & 63) * 64, d0 = (id >> 6) * 64;
    int t = threadIdx.x;
#pragma unroll
    for (int rr = 0; rr < 4; ++rr) {
      int r  = (t >> 4) + rr * 16;
      int cq = t & 15;
      float4 v = *(const float4*)(val + (size_t)(n0 + r) * 512 + d0 + cq * 4);
      Tt[cq*4+0][r] = (f16)v.x; Tt[cq*4+1][r] = (f16)v.y;
      Tt[cq*4+2][r] = (f16)v.z; Tt[cq*4+3][r] = (f16)v.w;
    }
    __syncthreads();
    int rd = t >> 2, part = t & 3;
    int p4 = part * 4;
    i32x4 pk;
    pk.x = pack4_fp8((float)Tt[rd][p4+0], (float)Tt[rd][16+p4+0],
                     (float)Tt[rd][32+p4+0], (float)Tt[rd][48+p4+0]);
    pk.y = pack4_fp8((float)Tt[rd][p4+1], (float)Tt[rd][16+p4+1],
                     (float)Tt[rd][32+p4+1], (float)Tt[rd][48+p4+1]);
    pk.z = pack4_fp8((float)Tt[rd][p4+2], (float)Tt[rd][16+p4+2],
                     (float)Tt[rd][32+p4+2], (float)Tt[rd][48+p4+2]);
    pk.w = pack4_fp8((float)Tt[rd][p4+3], (float)Tt[rd][16+p4+3],
                     (float)Tt[rd][32+p4+3], (float)Tt[rd][48+p4+3]);
    *(i32x4*)(Vt8 + (size_t)(d0 + rd) * 4096 + n0 + part * 16) = pk;
  } else {                             // invt: 16 blocks x 256
    int i = (b - 5632) * 256 + threadIdx.x;
    invt[i] = 1.0f / ((fabsf(T[i]) + 0.1f) * ns[i]);
  }
}

// ------------------------------------ per-tile norm bounds (after prep_all)
__global__ __launch_bounds__(64) void bounds_k(
    const float* __restrict__ x2, const float* __restrict__ p2,
    const float* __restrict__ invt, float* __restrict__ xb,
    float* __restrict__ nb) {
  int t = threadIdx.x;
  float lo, hi;
  if (blockIdx.x < 128) {
    int base = blockIdx.x * 128;
    float a = __builtin_amdgcn_sqrtf(x2[base + t]);
    float b = __builtin_amdgcn_sqrtf(x2[base + 64 + t]);
    lo = fminf(a, b); hi = fmaxf(a, b);
  } else {
    int base = (blockIdx.x - 128) * 128;
    float pa = __builtin_amdgcn_sqrtf(p2[base + t]);
    float pb = __builtin_amdgcn_sqrtf(p2[base + 64 + t]);
    float ra = 112.0f / invt[base + t];
    float rb = 112.0f / invt[base + 64 + t];
    lo = fminf(pa - ra, pb - rb); hi = fmaxf(pa + ra, pb + rb);
  }
#pragma unroll
  for (int s = 1; s < 64; s <<= 1) {
    lo = fminf(lo, __shfl_xor(lo, s));
    hi = fmaxf(hi, __shfl_xor(hi, s));
  }
  if (t == 0) {
    if (blockIdx.x < 128) { xb[blockIdx.x*2] = lo; xb[blockIdx.x*2+1] = hi; }
    else { int i = blockIdx.x - 128; nb[i*2] = lo; nb[i*2+1] = hi; }
  }
}

// ------------------------------------------------- main GEMM (C = A . B^T form)
// All-fp8. 128x128 tile, 4 waves 2x2, 4x4 16x16x32 frags/wave. K-tile 128 B.
// LDS dbuf [buf0|buf1] = 64KB; chunk-XOR swizzle; gload_lds pre-swz source.
// EPI 0 (pass A): triangle-skip N-loop x4; dense = 2-phase K-loop +
//   early-exit exp epilogue + permuted fp8 nt-stores + flags + Wpart.
// EPI 1 (pass B): rsum folded from Wpart into LDS slab; all-zero fast path
//   skips the whole K-loop; dense = block-sparse K-loop over flags.
template <int EPI>
__global__ __launch_bounds__(256, 2) void gemm_bt(
    const void* __restrict__ A, const void* __restrict__ B, int Kb, int gx,
    const float* __restrict__ x2, const float* __restrict__ p2,
    const float* __restrict__ invt, u8* __restrict__ Wout,
    float* __restrict__ Wpart, void* __restrict__ flagsp,
    const float* __restrict__ xb, const float* __restrict__ nb,
    float* __restrict__ outp) {
  __shared__ __align__(16) char smem[65536];
  char* As = smem;            // +cur: 0 or 32768
  char* Bs = smem + 16384;

  const int nwg = gridDim.x;
  const int sid = (blockIdx.x & 7) * (nwg >> 3) + (blockIdx.x >> 3);
  const int bx = sid % gx, by = sid / gx;

  const int tid = threadIdx.x, lane = tid & 63, w = tid >> 6;
  const int wrow = (w >> 1) * 64, wcol = (w & 1) * 64;
  const int g = lane >> 4, r15 = lane & 15;
  const int m0 = by * 128;

  const char* Ablk = (const char*)A + (size_t)m0 * Kb;

  const int lr = lane >> 3;
  const int lo = (lane & 7) ^ lr;
  const char* aSrc[4]; char* aDst[4]; char* bDst[4];
  int srow[4];
#pragma unroll
  for (int i = 0; i < 4; ++i) {
    int cb  = w * 4 + i;
    srow[i] = cb * 8 + lr;
    aSrc[i] = Ablk + (size_t)srow[i] * Kb + 16 * lo;
    aDst[i] = As + cb * 1024;
    bDst[i] = Bs + cb * 1024;
  }

  int abase[4], asw[4], bbase[4], bsw[4];
#pragma unroll
  for (int mt = 0; mt < 4; ++mt) {
    int r = wrow + mt * 16 + r15;
    abase[mt] = r * 128; asw[mt] = (r & 7) << 4;
    int rb = wcol + mt * 16 + r15;
    bbase[mt] = rb * 128; bsw[mt] = (rb & 7) << 4;
  }

  const int NIT = Kb >> 7;
  constexpr int nrep = (EPI == 0) ? 4 : 1;
  const u32* fl = (const u32*)flagsp;   // [Wmblock(128)][ntile(32)]

  // ---- pass B preamble: fold rowsum from Wpart (this block's 128 m-rows
  // = bx*128..), and detect the all-zero fast path (block-uniform).
  float* rsum = (float*)(smem + 40960);   // 128 f32, clear of Tb (<=33792)
  bool anyNZ = true;
  if constexpr (EPI == 1) {
    {
      int r = tid >> 1, half = tid & 1;
      const float* wp = Wpart + (size_t)(bx * 128 + r) * 64 + half;
      float v = 0.f;
#pragma unroll
      for (int t2 = 0; t2 < 32; ++t2) v += wp[t2 * 2];
      v += __shfl_xor(v, 1);
      if (half == 0) rsum[r] = v;
    }
    u32 f = (lane < 32) ? fl[bx * 32 + lane] : 0;
    anyNZ = __any(f != 0);               // same for all waves (same data)
    __syncthreads();                     // rsum visible to all
  }

  float xlo, xhi;
  if constexpr (EPI == 0) { xlo = xb[by * 2]; xhi = xb[by * 2 + 1]; }

  // pass B prologue staging (only on dense path)
  if constexpr (EPI == 1) {
    if (anyNZ && fl[bx * 32] != 0) {
      const char* Bblk0 = (const char*)B + (size_t)(bx * 128) * Kb;
#pragma unroll
      for (int i = 0; i < 4; ++i) gload16(aSrc[i], aDst[i]);
#pragma unroll
      for (int i = 0; i < 4; ++i)
        gload16(Bblk0 + (size_t)srow[i] * Kb + 16 * lo, bDst[i]);
    }
  }

  for (int j = 0; j < nrep; ++j) {
    const int bxj = bx * nrep + j;
    const int n0 = bxj * 128;

    if constexpr (EPI == 0) {
      // triangle-inequality tile skip (block-uniform, no divergence)
      float blo = nb[bxj * 2], bhi = nb[bxj * 2 + 1];
      if (xhi < blo || xlo > bhi) {
        if (lane == 0)
          ((u8*)flagsp)[(size_t)(by * 32 + bxj) * 4 + w] = 0;
        int r = tid >> 1, half = tid & 1;
        Wpart[(size_t)(m0 + r) * 64 + bxj * 2 + half] = 0.0f;
        continue;
      }
    }

    f32x4 acc[4][4] = {};
    bool dense = true;
    if constexpr (EPI == 1) dense = anyNZ;

    if (dense) {
      const char* Bblk = (const char*)B + (size_t)n0 * Kb;
      const char* bSrc[4];
#pragma unroll
      for (int i = 0; i < 4; ++i)
        bSrc[i] = Bblk + (size_t)srow[i] * Kb + 16 * lo;

      __syncthreads();   // retire previous epilogue's LDS reads
      if constexpr (EPI == 0) {
        // dense pass A stages its own tile0
#pragma unroll
        for (int i = 0; i < 4; ++i) gload16(aSrc[i], aDst[i]);
#pragma unroll
        for (int i = 0; i < 4; ++i) gload16(bSrc[i], bDst[i]);
        __syncthreads();
      }

#pragma unroll 2
      for (int it = 0; it < NIT; ++it) {
        const int cur = (it & 1) << 15;
        const int nxt = cur ^ 32768;
        bool fnx = true, fcu = true;
        if constexpr (EPI == 1) {
          fcu = fl[bx * 32 + it] != 0;
          if (it + 1 < NIT) fnx = fl[bx * 32 + it + 1] != 0;
        }
        if (it + 1 < NIT && fnx) {         // issue next-tile loads FIRST
          const int kb1 = (it + 1) << 7;
#pragma unroll
          for (int i = 0; i < 4; ++i) gload16(aSrc[i] + kb1, aDst[i] + nxt);
#pragma unroll
          for (int i = 0; i < 4; ++i) gload16(bSrc[i] + kb1, bDst[i] + nxt);
        }
        if (fcu) {                          // block-uniform
          const char* As_ = As + cur;
          const char* Bs_ = Bs + cur;
#pragma unroll
          for (int ks = 0; ks < 4; ++ks) {  // 4 k-slices of K=32 fp8
            long aL[4], bL[4];
#pragma unroll
            for (int mt = 0; mt < 4; ++mt)
              aL[mt] = *(const long*)(As_ + (abase[mt] + ((32 * ks + 8 * g) ^ asw[mt])));
#pragma unroll
            for (int nt = 0; nt < 4; ++nt)
              bL[nt] = *(const long*)(Bs_ + (bbase[nt] + ((32 * ks + 8 * g) ^ bsw[nt])));
#pragma unroll
            for (int mt = 0; mt < 4; ++mt)
#pragma unroll
              for (int nt = 0; nt < 4; ++nt)
                acc[mt][nt] = __builtin_amdgcn_mfma_f32_16x16x32_fp8_fp8(aL[mt], bL[nt],
                                                                         acc[mt][nt], 0, 0, 0);
          }
        }
        __syncthreads();
      }
    }

    if constexpr (EPI == 0) {
      // ---- dense pass A epilogue: EXACT early-exit exp + permuted fp8
      // nt-stores + Ws rowsum slab + nonzero flags.
      float* Ws = (float*)(smem + 32768);
      float p2v[4], itv[4], thr[4];
#pragma unroll
      for (int nt = 0; nt < 4; ++nt) {
        int n = n0 + wcol + nt * 16 + r15;
        p2v[nt] = p2[n]; itv[nt] = invt[n];
        float lim = 104.0f / itv[nt];
        thr[nt] = lim * lim;
      }
      u8* wbase = Wout + n0 + wcol + 4 * r15;
      bool tnz = false;
#pragma unroll
      for (int mt = 0; mt < 4; ++mt) {
#pragma unroll
        for (int reg = 0; reg < 4; ++reg) {
          int ml = wrow + mt * 16 + g * 4 + reg;
          float xx = x2[m0 + ml];
          float d20 = xx + p2v[0] - 2.0f * acc[mt][0][reg];
          float d21 = xx + p2v[1] - 2.0f * acc[mt][1][reg];
          float d22 = xx + p2v[2] - 2.0f * acc[mt][2][reg];
          float d23 = xx + p2v[3] - 2.0f * acc[mt][3][reg];
          int dw = 0;
          float s = 0.0f;
          bool pred = (d20 < thr[0]) || (d21 < thr[1]) ||
                      (d22 < thr[2]) || (d23 < thr[3]);
          if (__any(pred)) {
            float wv0 = __expf(-__builtin_amdgcn_sqrtf(fmaxf(d20, 0.0f)) * itv[0]);
            float wv1 = __expf(-__builtin_amdgcn_sqrtf(fmaxf(d21, 0.0f)) * itv[1]);
            float wv2 = __expf(-__builtin_amdgcn_sqrtf(fmaxf(d22, 0.0f)) * itv[2]);
            float wv3 = __expf(-__builtin_amdgcn_sqrtf(fmaxf(d23, 0.0f)) * itv[3]);
            dw = pack4_fp8(wv0, wv1, wv2, wv3);
            s = wv0 + wv1 + wv2 + wv3;
            tnz = tnz || (dw != 0);
          }
          __builtin_nontemporal_store(dw, (int*)(wbase + (size_t)(m0 + ml) * 4096));
          Ws[ml * 36 + (w & 1) * 16 + r15] = s;
        }
      }
      {
        bool wnz = __any(tnz);
        if (lane == 0)
          ((u8*)flagsp)[(size_t)(by * 32 + bxj) * 4 + w] = wnz ? 1 : 0;
      }
      __syncthreads();
      {
        int r = tid >> 1, half = tid & 1;
        const float* sp = Ws + r * 36 + half * 16;
        float4 a0 = *(const float4*)(sp);
        float4 a1 = *(const float4*)(sp + 4);
        float4 a2 = *(const float4*)(sp + 8);
        float4 a3 = *(const float4*)(sp + 12);
        float s = a0.x+a0.y+a0.z+a0.w + a1.x+a1.y+a1.z+a1.w
                + a2.x+a2.y+a2.z+a2.w + a3.x+a3.y+a3.z+a3.w;
        Wpart[(size_t)(m0 + r) * 64 + bxj * 2 + half] = s;
      }
    } else {
      // ---- pass B epilogue: O^T transpose via per-wave LDS + normalize
      // (rsum from the folded LDS slab; acc==0 on the fast path).
      float* Tb = (float*)(smem) + w * (32 * 66);
      const int dl = lane & 31, half = lane >> 5;
#pragma unroll
      for (int h = 0; h < 2; ++h) {
#pragma unroll
        for (int mh = 0; mh < 2; ++mh) {
          int mt = h * 2 + mh;
#pragma unroll
          for (int nt = 0; nt < 4; ++nt)
#pragma unroll
            for (int reg = 0; reg < 4; ++reg)
              Tb[(mh * 16 + g * 4 + reg) * 66 + nt * 16 + r15] = acc[mt][nt][reg];
        }
#pragma unroll
        for (int rr = 0; rr < 32; ++rr) {
          int mloc = rr * 2 + half;
          float v = Tb[dl * 66 + mloc];
          int mg = n0 + wcol + mloc;
          int dg = m0 + wrow + h * 32 + dl;
          float nrm = 1.0f / (rsum[wcol + mloc] + 1e-8f);
          __builtin_nontemporal_store(v * nrm, &outp[(size_t)mg * 512 + dg]);
        }
        __syncthreads();  // Tb reused next h
      }
    }
  }
}

// ---------------------------------------------------------------------- launch

extern "C" void kernel_launch(void* const* d_in, const int* in_sizes, int n_in,
                              void* d_out, int out_size, void* d_ws, size_t ws_size,
                              hipStream_t stream) {
  const float* x   = (const float*)d_in[0];
  const float* pos = (const float*)d_in[1];
  const float* val = (const float*)d_in[2];
  const float* tmp = (const float*)d_in[3];
  const float* nsc = (const float*)d_in[4];
  float* out = (float*)d_out;

  char* p = (char*)d_ws;
  u8*    X8     = (u8*)p;    p += (size_t)16384 * 512;
  u8*    P8     = (u8*)p;    p += (size_t)4096 * 512;
  u8*    Vt8    = (u8*)p;    p += (size_t)512 * 4096;
  float* x2     = (float*)p; p += (size_t)16384 * 4;
  float* p2     = (float*)p; p += (size_t)4096 * 4;
  float* invt   = (float*)p; p += (size_t)4096 * 4;
  float* Wpart  = (float*)p; p += (size_t)16384 * 64 * 4;
  void*  flags  = (void*)p;  p += (size_t)128 * 32 * 4;   // tile nz flags
  float* xb     = (float*)p; p += (size_t)128 * 2 * 4;    // m-tile |x| bounds
  float* nb     = (float*)p; p += (size_t)32 * 2 * 4;     // n-tile bands
  u8*    W8     = (u8*)p;
  size_t fixed  = (size_t)(p - (char*)d_ws);
  size_t wfull  = (size_t)16384 * 4096;   // fp8 W

  if (fixed + wfull > ws_size) return;

  prep_all<<<5648, 256, 0, stream>>>(x, pos, val, tmp, nsc,
                                     X8, P8, Vt8, x2, p2, invt);
  bounds_k<<<160, 64, 0, stream>>>(x2, p2, invt, xb, nb);

  // pass A: Kb = 512 fp8 bytes/row, NIT = 4, N-loop x4 -> grid 8 * 128
  gemm_bt<0><<<8 * 128, 256, 0, stream>>>(
      X8, P8, 512, 8, x2, p2, invt, W8, Wpart, flags, xb, nb, nullptr);
  // pass B: Kb = 4096, NIT = 32, block-sparse + folded rowsum + fast path
  gemm_bt<1><<<128 * 4, 256, 0, stream>>>(
      Vt8, W8, 4096, 128, nullptr, nullptr, nullptr, nullptr, Wpart, flags,
      nullptr, nullptr, out);
}